// Round 2
// baseline (504.696 us; speedup 1.0000x reference)
//
#include <hip/hip_runtime.h>
#include <hip/hip_bf16.h>

// MaskedMoE: T=2048, d=1024, d_ff=4096, E=8, top-2.
// R5 (resubmit — prior round was an infra failure, kernel never ran):
//   LDS-free register transpose + chunk-major weight tiles.
//   WT layout: [e][kt][ntile][ch(8)][n(128)][8 f16]  (tile slot j = ch*128 + n, linear).
//   Transpose: each thread loads 8 k-rows x 4 n as float4 (wave reads 1KB/row,
//   coalesced), transposes in registers, writes 64B contiguous. No LDS, no barrier.
//   GEMM B-staging identical (contiguous 16KB slab via global_load_lds); consumer
//   B-fragment address becomes (ch*128 + n)*8 with ch = lhi (+4 for 2nd k-half).
//   A path unchanged (row-major + chunk-pos XOR, staged via per-lane gather).

#define T_TOK 2048
#define D_EMB 1024
#define DFF   4096
#define NE    8

typedef _Float16 f16x8 __attribute__((ext_vector_type(8)));
typedef float    f32x4 __attribute__((ext_vector_type(4)));

__device__ __forceinline__ float gelu_tanh(float x) {
    const float c = 0.7978845608028654f;
    float z = c * (x + 0.044715f * x * x * x);
    float u = __expf(2.0f * z);
    return 0.5f * x * (1.0f + (u - 1.0f) / (u + 1.0f));
}

__device__ __forceinline__ void gll(const void* g, void* l) {
    __builtin_amdgcn_global_load_lds((__attribute__((address_space(1))) void*)g,
                                     (__attribute__((address_space(3))) void*)l,
                                     16, 0, 0);
}

__global__ void k_zero(int* counts) {
    if (threadIdx.x < NE) counts[threadIdx.x] = 0;
}

// Router (one wave/token) + fp16 conversion of x fused.
__global__ __launch_bounds__(256) void k_router(
    const float* __restrict__ x, const float* __restrict__ mask,
    const float* __restrict__ Wr, _Float16* __restrict__ xh,
    int* __restrict__ counts, int* __restrict__ elist,
    int* __restrict__ tok_e, int* __restrict__ tok_p, float* __restrict__ tok_w) {
    int wave = threadIdx.x >> 6;
    int lane = threadIdx.x & 63;
    int t = blockIdx.x * 4 + wave;
    if (t >= T_TOK) return;

    float acc[NE];
#pragma unroll
    for (int e = 0; e < NE; e++) acc[e] = 0.f;
    const float* xr = x + (size_t)t * D_EMB;
    for (int c = 0; c < D_EMB / 64; c++) {
        int i = c * 64 + lane;
        float xv = xr[i];
        xh[(size_t)t * D_EMB + i] = (_Float16)xv;
        const float* wr = Wr + (size_t)i * NE;
#pragma unroll
        for (int e = 0; e < NE; e++) acc[e] += xv * wr[e];
    }
#pragma unroll
    for (int e = 0; e < NE; e++) {
#pragma unroll
        for (int off = 32; off > 0; off >>= 1)
            acc[e] += __shfl_xor(acc[e], off);
    }
    if (lane == 0) {
        float p[NE];
        float mx = -1e30f;
#pragma unroll
        for (int e = 0; e < NE; e++) {
            p[e] = acc[e] * mask[t * NE + e];
            mx = fmaxf(mx, p[e]);
        }
        float s = 0.f;
#pragma unroll
        for (int e = 0; e < NE; e++) { p[e] = expf(p[e] - mx); s += p[e]; }
#pragma unroll
        for (int e = 0; e < NE; e++) p[e] /= s;
        int e0 = 0; float b0 = p[0];
#pragma unroll
        for (int e = 1; e < NE; e++) if (p[e] > b0) { b0 = p[e]; e0 = e; }
        int e1 = -1; float b1 = -1.f;
#pragma unroll
        for (int e = 0; e < NE; e++) if (e != e0 && p[e] > b1) { b1 = p[e]; e1 = e; }

        int pos0 = atomicAdd(&counts[e0], 1);
        elist[e0 * T_TOK + pos0] = t;
        tok_e[t * 2 + 0] = e0; tok_p[t * 2 + 0] = pos0; tok_w[t * 2 + 0] = b0;
        int pos1 = atomicAdd(&counts[e1], 1);
        elist[e1 * T_TOK + pos1] = t;
        tok_e[t * 2 + 1] = e1; tok_p[t * 2 + 1] = pos1; tok_w[t * 2 + 1] = b1;
    }
}

// LDS-free transpose: fp32 [K][N] -> chunk-major fp16 tiles [kt][ntile][ch][n][8].
// z<8: W1 expert z (K=1024,N=4096, NT=32, kt-plane stride 262144 halfwords)
// z>=8: W2 expert z-8 (K=4096,N=1024, NT=8, kt-plane stride 65536 halfwords)
// Block = one k-chunk g (8 rows) x 1024 n. Thread = 8 rows x 4 n, all in registers.
__global__ __launch_bounds__(256) void k_transpose(
    const float* __restrict__ W1, const float* __restrict__ W2,
    _Float16* __restrict__ W1T, _Float16* __restrict__ W2T) {
    int bz = blockIdx.z;
    int e = bz & 7;
    bool isW2 = bz >= 8;
    const float* S = (isW2 ? W2 : W1) + (size_t)e * 4194304;
    _Float16* Dst = (isW2 ? W2T : W1T) + (size_t)e * 4194304;
    int ld      = isW2 ? 1024 : 4096;      // source row length (floats)
    int ktplane = isW2 ? 65536 : 262144;   // kt-plane stride (halfwords) = NT*8192
    int bx = blockIdx.x;
    int g, nb;
    if (isW2) { g = bx; nb = 0; }
    else      { g = bx >> 2; nb = (bx & 3) * 1024; }

    int t = threadIdx.x;
    int n = nb + t * 4;
    const float* src = S + (size_t)(g * 8) * ld + n;

    f32x4 v[8];
#pragma unroll
    for (int r = 0; r < 8; r++)
        v[r] = *(const f32x4*)(src + (size_t)r * ld);

    f16x8 o[4];
#pragma unroll
    for (int j = 0; j < 4; j++)
#pragma unroll
        for (int u = 0; u < 8; u++)
            o[j][u] = (_Float16)v[u][j];

    size_t off = (size_t)(g >> 3) * ktplane + (size_t)(n >> 7) * 8192
               + (g & 7) * 1024 + (n & 127) * 8;
    f16x8* d = (f16x8*)(Dst + off);
#pragma unroll
    for (int j = 0; j < 4; j++) d[j] = o[j];   // 64B contiguous per thread
}

// ---- GEMM core --------------------------------------------------------------
// A LDS tile: 128 rows x 8 chunks x 8 f16; position p of row r holds chunk p^(r&7).
//   A producer gathers rows with per-lane chunk cch=(tid&7)^((tid>>3)&7);
//   A consumer: kcA0 = lhi ^ (llo&7), kcA1 = kcA0^4.
// B LDS tile: chunk-major [ch(8)][n(128)][8 f16] — identity copy of the
//   pre-transposed plane; consumer reads chunk lhi (and lhi+4) at col n.

// GEMM1: H[rowbase+p, :] = gelu(xh[elist[e,p], :] @ W1[e]). K=1024, 16 iters.
__global__ __launch_bounds__(256) void k_gemm1(
    const _Float16* __restrict__ xh, const _Float16* __restrict__ BT,
    const int* __restrict__ counts, const int* __restrict__ elist,
    _Float16* __restrict__ H) {
    int e = blockIdx.z;
    int cnt = counts[e];
    int p0 = blockIdx.y * 128;
    if (p0 >= cnt) return;
    int rowbase = 0;
    for (int i = 0; i < NE; i++) rowbase += (i < e) ? counts[i] : 0;
    int n0 = blockIdx.x * 128;
    const _Float16* B = BT + (size_t)e * 4194304;   // tiled: [kt16][nt32][8][128][8]

    __shared__ _Float16 As[128 * 64];
    __shared__ _Float16 Bs[128 * 64];
    __shared__ int ttok[128];

    int tid = threadIdx.x;
    if (tid < 128) ttok[tid] = elist[e * T_TOK + min(p0 + tid, cnt - 1)];
    __syncthreads();

    int w = tid >> 6, lane = tid & 63;
    int rq = tid >> 3;
    int cch = (tid & 7) ^ ((tid >> 3) & 7);
    const _Float16* pA[4];
    const _Float16* pB[4];
    _Float16* lA[4];
    _Float16* lB[4];
#pragma unroll
    for (int q = 0; q < 4; q++) {
        int row = q * 32 + rq;
        pA[q] = xh + (size_t)ttok[row] * D_EMB + cch * 8;
        pB[q] = B + (size_t)n0 * 64 + (q * 256 + tid) * 8;   // contiguous 16KB slab
        lA[q] = As + (q * 256 + w * 64) * 8;
        lB[q] = Bs + (q * 256 + w * 64) * 8;
    }

    int wm = w >> 1, wn = w & 1;
    int lhi = lane >> 4, llo = lane & 15;
    int m7 = llo & 7;
    int kc0 = lhi ^ m7, kc1 = kc0 ^ 4;
    const _Float16* arp0 = As + (wm * 64 + llo) * 64 + kc0 * 8;
    const _Float16* arp1 = As + (wm * 64 + llo) * 64 + kc1 * 8;
    const _Float16* brp0 = Bs + (lhi * 128 + wn * 64 + llo) * 8;
    const _Float16* brp1 = Bs + ((lhi + 4) * 128 + wn * 64 + llo) * 8;

    f32x4 acc[4][4] = {};
    for (int it = 0; it < 16; ++it) {
        __syncthreads();
#pragma unroll
        for (int q = 0; q < 4; q++) { gll(pA[q], lA[q]); gll(pB[q], lB[q]); }
#pragma unroll
        for (int q = 0; q < 4; q++) { pA[q] += 64; pB[q] += 262144; }
        __syncthreads();
        f16x8 a[4], b[4];
#pragma unroll
        for (int i = 0; i < 4; i++) {
            a[i] = *(const f16x8*)(arp0 + i * 1024);
            b[i] = *(const f16x8*)(brp0 + i * 128);
        }
#pragma unroll
        for (int mt = 0; mt < 4; mt++)
#pragma unroll
            for (int nt = 0; nt < 4; nt++)
                acc[mt][nt] = __builtin_amdgcn_mfma_f32_16x16x32_f16(a[mt], b[nt], acc[mt][nt], 0, 0, 0);
#pragma unroll
        for (int i = 0; i < 4; i++) {
            a[i] = *(const f16x8*)(arp1 + i * 1024);
            b[i] = *(const f16x8*)(brp1 + i * 128);
        }
#pragma unroll
        for (int mt = 0; mt < 4; mt++)
#pragma unroll
            for (int nt = 0; nt < 4; nt++)
                acc[mt][nt] = __builtin_amdgcn_mfma_f32_16x16x32_f16(a[mt], b[nt], acc[mt][nt], 0, 0, 0);
    }

#pragma unroll
    for (int mt = 0; mt < 4; mt++) {
#pragma unroll
        for (int i = 0; i < 4; i++) {
            int p = p0 + wm * 64 + mt * 16 + lhi * 4 + i;
            if (p < cnt) {
                size_t rowoff = (size_t)(rowbase + p) * DFF + n0 + wn * 64 + llo;
#pragma unroll
                for (int nt = 0; nt < 4; nt++)
                    H[rowoff + nt * 16] = (_Float16)gelu_tanh(acc[mt][nt][i]);
            }
        }
    }
}

// GEMM2 split-K=4: O[sp][row, :] = H[row, sp*1024..+1024] @ W2[e][same k][:]. 16 iters.
__global__ __launch_bounds__(256) void k_gemm2(
    const _Float16* __restrict__ H, const _Float16* __restrict__ BT,
    const int* __restrict__ counts, float* __restrict__ Obase) {
    int bz = blockIdx.z;
    int e = bz & 7, sp = bz >> 3;
    int cnt = counts[e];
    int p0 = blockIdx.y * 128;
    if (p0 >= cnt) return;
    int rowbase = 0;
    for (int i = 0; i < NE; i++) rowbase += (i < e) ? counts[i] : 0;
    int n0 = blockIdx.x * 128;
    int kh = sp * 1024;
    const _Float16* B = BT + (size_t)e * 4194304;   // tiled: [kt64][nt8][8][128][8]
    float* O = Obase + (size_t)sp * 4194304;

    __shared__ _Float16 As[128 * 64];
    __shared__ _Float16 Bs[128 * 64];

    int tid = threadIdx.x;
    int w = tid >> 6, lane = tid & 63;
    int rq = tid >> 3;
    int cch = (tid & 7) ^ ((tid >> 3) & 7);
    const _Float16* pA[4];
    const _Float16* pB[4];
    _Float16* lA[4];
    _Float16* lB[4];
#pragma unroll
    for (int q = 0; q < 4; q++) {
        int row = q * 32 + rq;
        int r = rowbase + min(p0 + row, cnt - 1);
        pA[q] = H + (size_t)r * DFF + kh + cch * 8;
        pB[q] = B + (size_t)(sp * 16) * 65536 + (size_t)n0 * 64 + (q * 256 + tid) * 8;
        lA[q] = As + (q * 256 + w * 64) * 8;
        lB[q] = Bs + (q * 256 + w * 64) * 8;
    }

    int wm = w >> 1, wn = w & 1;
    int lhi = lane >> 4, llo = lane & 15;
    int m7 = llo & 7;
    int kc0 = lhi ^ m7, kc1 = kc0 ^ 4;
    const _Float16* arp0 = As + (wm * 64 + llo) * 64 + kc0 * 8;
    const _Float16* arp1 = As + (wm * 64 + llo) * 64 + kc1 * 8;
    const _Float16* brp0 = Bs + (lhi * 128 + wn * 64 + llo) * 8;
    const _Float16* brp1 = Bs + ((lhi + 4) * 128 + wn * 64 + llo) * 8;

    f32x4 acc[4][4] = {};
    for (int it = 0; it < 16; ++it) {
        __syncthreads();
#pragma unroll
        for (int q = 0; q < 4; q++) { gll(pA[q], lA[q]); gll(pB[q], lB[q]); }
#pragma unroll
        for (int q = 0; q < 4; q++) { pA[q] += 64; pB[q] += 65536; }
        __syncthreads();
        f16x8 a[4], b[4];
#pragma unroll
        for (int i = 0; i < 4; i++) {
            a[i] = *(const f16x8*)(arp0 + i * 1024);
            b[i] = *(const f16x8*)(brp0 + i * 128);
        }
#pragma unroll
        for (int mt = 0; mt < 4; mt++)
#pragma unroll
            for (int nt = 0; nt < 4; nt++)
                acc[mt][nt] = __builtin_amdgcn_mfma_f32_16x16x32_f16(a[mt], b[nt], acc[mt][nt], 0, 0, 0);
#pragma unroll
        for (int i = 0; i < 4; i++) {
            a[i] = *(const f16x8*)(arp1 + i * 1024);
            b[i] = *(const f16x8*)(brp1 + i * 128);
        }
#pragma unroll
        for (int mt = 0; mt < 4; mt++)
#pragma unroll
            for (int nt = 0; nt < 4; nt++)
                acc[mt][nt] = __builtin_amdgcn_mfma_f32_16x16x32_f16(a[mt], b[nt], acc[mt][nt], 0, 0, 0);
    }

#pragma unroll
    for (int mt = 0; mt < 4; mt++) {
#pragma unroll
        for (int i = 0; i < 4; i++) {
            int p = p0 + wm * 64 + mt * 16 + lhi * 4 + i;
            if (p < cnt) {
                size_t o = (size_t)(rowbase + p) * D_EMB + n0 + wn * 64 + llo;
#pragma unroll
                for (int nt = 0; nt < 4; nt++)
                    O[o + nt * 16] = acc[mt][nt][i];
            }
        }
    }
}

// out[t,:] = w0*sum_sp Osp[r0] + w1*sum_sp Osp[r1]
__global__ __launch_bounds__(256) void k_final(
    const float* __restrict__ Obase, const int* __restrict__ counts,
    const int* __restrict__ tok_e, const int* __restrict__ tok_p,
    const float* __restrict__ tok_w, float* __restrict__ out) {
    __shared__ int sb[NE];
    int t = blockIdx.x;
    if (threadIdx.x == 0) {
        int s = 0;
        for (int e = 0; e < NE; e++) { sb[e] = s; s += counts[e]; }
    }
    __syncthreads();
    int r0 = sb[tok_e[t * 2 + 0]] + tok_p[t * 2 + 0];
    int r1 = sb[tok_e[t * 2 + 1]] + tok_p[t * 2 + 1];
    float w0 = tok_w[t * 2 + 0], w1 = tok_w[t * 2 + 1];
    int i = threadIdx.x * 4;
    float4 s0 = {0, 0, 0, 0}, s1 = {0, 0, 0, 0};
#pragma unroll
    for (int sp = 0; sp < 4; sp++) {
        const float* O = Obase + (size_t)sp * 4194304;
        float4 a = *(const float4*)(O + (size_t)r0 * D_EMB + i);
        float4 b = *(const float4*)(O + (size_t)r1 * D_EMB + i);
        s0.x += a.x; s0.y += a.y; s0.z += a.z; s0.w += a.w;
        s1.x += b.x; s1.y += b.y; s1.z += b.z; s1.w += b.w;
    }
    float4 o;
    o.x = w0 * s0.x + w1 * s1.x;
    o.y = w0 * s0.y + w1 * s1.y;
    o.z = w0 * s0.z + w1 * s1.z;
    o.w = w0 * s0.w + w1 * s1.w;
    *(float4*)(out + (size_t)t * D_EMB + i) = o;
}

extern "C" void kernel_launch(void* const* d_in, const int* in_sizes, int n_in,
                              void* d_out, int out_size, void* d_ws, size_t ws_size,
                              hipStream_t stream) {
    const float* x    = (const float*)d_in[0];
    const float* mask = (const float*)d_in[1];
    const float* Wr   = (const float*)d_in[2];
    const float* W1   = (const float*)d_in[3];   // [8,1024,4096]
    const float* W2   = (const float*)d_in[4];   // [8,4096,1024]
    float* out = (float*)d_out;

    char* ws = (char*)d_ws;
    const size_t MB = 1024 * 1024;
    int*      counts = (int*)(ws + 0);
    int*      elist  = (int*)(ws + 1024);
    int*      tok_e  = (int*)(ws + 1024 + 65536);
    int*      tok_p  = (int*)(ws + 1024 + 65536 + 16384);
    float*    tok_w  = (float*)(ws + 1024 + 65536 + 32768);
    _Float16* xh     = (_Float16*)(ws + 1 * MB);    // 4 MB
    _Float16* W1T    = (_Float16*)(ws + 8 * MB);    // 64 MB tiled [e][kt16][nt32][8][128][8]
    _Float16* W2T    = (_Float16*)(ws + 72 * MB);   // 64 MB tiled [e][kt64][nt8][8][128][8]
    _Float16* H      = (_Float16*)(ws + 136 * MB);  // 32 MB [4096][4096]
    float*    Obuf   = (float*)(ws + 168 * MB);     // 64 MB [4 sp][4096][1024]

    k_zero<<<1, 64, 0, stream>>>(counts);
    k_router<<<T_TOK / 4, 256, 0, stream>>>(x, mask, Wr, xh, counts, elist, tok_e, tok_p, tok_w);
    k_transpose<<<dim3(512, 1, 16), 256, 0, stream>>>(W1, W2, W1T, W2T);
    k_gemm1<<<dim3(32, 16, NE), 256, 0, stream>>>(xh, W1T, counts, elist, H);
    k_gemm2<<<dim3(8, 16, 32), 256, 0, stream>>>(H, W2T, counts, Obuf);
    k_final<<<T_TOK, 256, 0, stream>>>(Obuf, counts, tok_e, tok_p, tok_w, out);
}

// Round 3
// 499.319 us; speedup vs baseline: 1.0108x; 1.0108x over previous
//
#include <hip/hip_runtime.h>
#include <hip/hip_bf16.h>

// MaskedMoE: T=2048, d=1024, d_ff=4096, E=8, top-2.
// R6: hide the weight-transpose under independent work via grid fusion.
//   Evidence: R4 (LDS 2-phase, 32% occ) and R5 (LDS-free, 71% occ) both pin at
//   ~2.4 TB/s HBM on the transpose -> pattern-limited, not structure-limited.
//   So overlap it instead:
//     k_f1 = router (512 blocks) + transpose-W1 (4096 blocks)
//     k_f2 = gemm1 (even blocks) interleaved 1:1 with transpose-W2 (odd blocks)
//   Inner bodies identical to R5 (verified, absmax 0.0039).
//   Dependences preserved by stream order: k_f1 -> k_f2 -> gemm2 -> final.

#define T_TOK 2048
#define D_EMB 1024
#define DFF   4096
#define NE    8

typedef _Float16 f16x8 __attribute__((ext_vector_type(8)));
typedef float    f32x4 __attribute__((ext_vector_type(4)));

__device__ __forceinline__ float gelu_tanh(float x) {
    const float c = 0.7978845608028654f;
    float z = c * (x + 0.044715f * x * x * x);
    float u = __expf(2.0f * z);
    return 0.5f * x * (1.0f + (u - 1.0f) / (u + 1.0f));
}

__device__ __forceinline__ void gll(const void* g, void* l) {
    __builtin_amdgcn_global_load_lds((__attribute__((address_space(1))) void*)g,
                                     (__attribute__((address_space(3))) void*)l,
                                     16, 0, 0);
}

__global__ void k_zero(int* counts) {
    if (threadIdx.x < NE) counts[threadIdx.x] = 0;
}

// LDS-free register transpose of one 8k x 1024n block:
// fp32 [K][N] -> chunk-major fp16 tile [kt][ntile][ch(8)][n(128)][8].
__device__ __forceinline__ void transpose_body(
    const float* __restrict__ S, _Float16* __restrict__ Dst,
    int ld, int ktplane, int g, int nb, int tid) {
    int n = nb + tid * 4;
    const float* src = S + (size_t)(g * 8) * ld + n;
    f32x4 v[8];
#pragma unroll
    for (int r = 0; r < 8; r++)
        v[r] = *(const f32x4*)(src + (size_t)r * ld);
    f16x8 o[4];
#pragma unroll
    for (int j = 0; j < 4; j++)
#pragma unroll
        for (int u = 0; u < 8; u++)
            o[j][u] = (_Float16)v[u][j];
    size_t off = (size_t)(g >> 3) * ktplane + (size_t)(n >> 7) * 8192
               + (g & 7) * 1024 + (n & 127) * 8;
    f16x8* d = (f16x8*)(Dst + off);
#pragma unroll
    for (int j = 0; j < 4; j++) d[j] = o[j];   // 64B contiguous per thread
}

// Fused kernel 1: router (blocks 0..511) + transpose of W1 (blocks 512..4607).
__global__ __launch_bounds__(256) void k_f1(
    const float* __restrict__ x, const float* __restrict__ mask,
    const float* __restrict__ Wr, _Float16* __restrict__ xh,
    int* __restrict__ counts, int* __restrict__ elist,
    int* __restrict__ tok_e, int* __restrict__ tok_p, float* __restrict__ tok_w,
    const float* __restrict__ W1, _Float16* __restrict__ W1T) {
    int bid = blockIdx.x;
    if (bid >= 512) {
        int idx = bid - 512;
        int e = idx >> 9, bx = idx & 511;
        transpose_body(W1 + (size_t)e * 4194304, W1T + (size_t)e * 4194304,
                       4096, 262144, bx >> 2, (bx & 3) * 1024, threadIdx.x);
        return;
    }
    // ---- router: one wave per token, 4 tokens per block ----
    int wave = threadIdx.x >> 6;
    int lane = threadIdx.x & 63;
    int t = bid * 4 + wave;

    float acc[NE];
#pragma unroll
    for (int e = 0; e < NE; e++) acc[e] = 0.f;
    const float* xr = x + (size_t)t * D_EMB;
    for (int c = 0; c < D_EMB / 64; c++) {
        int i = c * 64 + lane;
        float xv = xr[i];
        xh[(size_t)t * D_EMB + i] = (_Float16)xv;
        const float* wr = Wr + (size_t)i * NE;
#pragma unroll
        for (int e = 0; e < NE; e++) acc[e] += xv * wr[e];
    }
#pragma unroll
    for (int e = 0; e < NE; e++) {
#pragma unroll
        for (int off = 32; off > 0; off >>= 1)
            acc[e] += __shfl_xor(acc[e], off);
    }
    if (lane == 0) {
        float p[NE];
        float mx = -1e30f;
#pragma unroll
        for (int e = 0; e < NE; e++) {
            p[e] = acc[e] * mask[t * NE + e];
            mx = fmaxf(mx, p[e]);
        }
        float s = 0.f;
#pragma unroll
        for (int e = 0; e < NE; e++) { p[e] = expf(p[e] - mx); s += p[e]; }
#pragma unroll
        for (int e = 0; e < NE; e++) p[e] /= s;
        int e0 = 0; float b0 = p[0];
#pragma unroll
        for (int e = 1; e < NE; e++) if (p[e] > b0) { b0 = p[e]; e0 = e; }
        int e1 = -1; float b1 = -1.f;
#pragma unroll
        for (int e = 0; e < NE; e++) if (e != e0 && p[e] > b1) { b1 = p[e]; e1 = e; }

        int pos0 = atomicAdd(&counts[e0], 1);
        elist[e0 * T_TOK + pos0] = t;
        tok_e[t * 2 + 0] = e0; tok_p[t * 2 + 0] = pos0; tok_w[t * 2 + 0] = b0;
        int pos1 = atomicAdd(&counts[e1], 1);
        elist[e1 * T_TOK + pos1] = t;
        tok_e[t * 2 + 1] = e1; tok_p[t * 2 + 1] = pos1; tok_w[t * 2 + 1] = b1;
    }
}

// ---- GEMM core --------------------------------------------------------------
// A LDS tile: 128 rows x 8 chunks x 8 f16; position p of row r holds chunk p^(r&7).
//   A producer gathers rows with per-lane chunk cch=(tid&7)^((tid>>3)&7);
//   A consumer: kcA0 = lhi ^ (llo&7), kcA1 = kcA0^4.
// B LDS tile: chunk-major [ch(8)][n(128)][8 f16] — identity copy of the
//   pre-transposed plane; consumer reads chunk lhi (and lhi+4) at col n.

// Fused kernel 2: gemm1 (even blocks) interleaved with transpose of W2 (odd).
// GEMM1: H[rowbase+p, :] = gelu(xh[elist[e,p], :] @ W1[e]). K=1024, 16 iters.
__global__ __launch_bounds__(256) void k_f2(
    const _Float16* __restrict__ xh, const _Float16* __restrict__ BT,
    const int* __restrict__ counts, const int* __restrict__ elist,
    _Float16* __restrict__ H,
    const float* __restrict__ W2, _Float16* __restrict__ W2T) {
    int bid = blockIdx.x;
    int tid = threadIdx.x;
    if (bid & 1) {
        int idx = bid >> 1;
        int e = idx >> 9, bx = idx & 511;
        transpose_body(W2 + (size_t)e * 4194304, W2T + (size_t)e * 4194304,
                       1024, 65536, bx, 0, tid);
        return;
    }
    int gid = bid >> 1;
    int e = gid >> 9;
    int cnt = counts[e];
    int p0 = ((gid >> 5) & 15) * 128;
    if (p0 >= cnt) return;
    int rowbase = 0;
    for (int i = 0; i < NE; i++) rowbase += (i < e) ? counts[i] : 0;
    int n0 = (gid & 31) * 128;
    const _Float16* B = BT + (size_t)e * 4194304;   // tiled: [kt16][nt32][8][128][8]

    __shared__ _Float16 As[128 * 64];
    __shared__ _Float16 Bs[128 * 64];
    __shared__ int ttok[128];

    if (tid < 128) ttok[tid] = elist[e * T_TOK + min(p0 + tid, cnt - 1)];
    __syncthreads();

    int w = tid >> 6, lane = tid & 63;
    int rq = tid >> 3;
    int cch = (tid & 7) ^ ((tid >> 3) & 7);
    const _Float16* pA[4];
    const _Float16* pB[4];
    _Float16* lA[4];
    _Float16* lB[4];
#pragma unroll
    for (int q = 0; q < 4; q++) {
        int row = q * 32 + rq;
        pA[q] = xh + (size_t)ttok[row] * D_EMB + cch * 8;
        pB[q] = B + (size_t)n0 * 64 + (q * 256 + tid) * 8;   // contiguous 16KB slab
        lA[q] = As + (q * 256 + w * 64) * 8;
        lB[q] = Bs + (q * 256 + w * 64) * 8;
    }

    int wm = w >> 1, wn = w & 1;
    int lhi = lane >> 4, llo = lane & 15;
    int m7 = llo & 7;
    int kc0 = lhi ^ m7, kc1 = kc0 ^ 4;
    const _Float16* arp0 = As + (wm * 64 + llo) * 64 + kc0 * 8;
    const _Float16* arp1 = As + (wm * 64 + llo) * 64 + kc1 * 8;
    const _Float16* brp0 = Bs + (lhi * 128 + wn * 64 + llo) * 8;
    const _Float16* brp1 = Bs + ((lhi + 4) * 128 + wn * 64 + llo) * 8;

    f32x4 acc[4][4] = {};
    for (int it = 0; it < 16; ++it) {
        __syncthreads();
#pragma unroll
        for (int q = 0; q < 4; q++) { gll(pA[q], lA[q]); gll(pB[q], lB[q]); }
#pragma unroll
        for (int q = 0; q < 4; q++) { pA[q] += 64; pB[q] += 262144; }
        __syncthreads();
        f16x8 a[4], b[4];
#pragma unroll
        for (int i = 0; i < 4; i++) {
            a[i] = *(const f16x8*)(arp0 + i * 1024);
            b[i] = *(const f16x8*)(brp0 + i * 128);
        }
#pragma unroll
        for (int mt = 0; mt < 4; mt++)
#pragma unroll
            for (int nt = 0; nt < 4; nt++)
                acc[mt][nt] = __builtin_amdgcn_mfma_f32_16x16x32_f16(a[mt], b[nt], acc[mt][nt], 0, 0, 0);
#pragma unroll
        for (int i = 0; i < 4; i++) {
            a[i] = *(const f16x8*)(arp1 + i * 1024);
            b[i] = *(const f16x8*)(brp1 + i * 128);
        }
#pragma unroll
        for (int mt = 0; mt < 4; mt++)
#pragma unroll
            for (int nt = 0; nt < 4; nt++)
                acc[mt][nt] = __builtin_amdgcn_mfma_f32_16x16x32_f16(a[mt], b[nt], acc[mt][nt], 0, 0, 0);
    }

#pragma unroll
    for (int mt = 0; mt < 4; mt++) {
#pragma unroll
        for (int i = 0; i < 4; i++) {
            int p = p0 + wm * 64 + mt * 16 + lhi * 4 + i;
            if (p < cnt) {
                size_t rowoff = (size_t)(rowbase + p) * DFF + n0 + wn * 64 + llo;
#pragma unroll
                for (int nt = 0; nt < 4; nt++)
                    H[rowoff + nt * 16] = (_Float16)gelu_tanh(acc[mt][nt][i]);
            }
        }
    }
}

// GEMM2 split-K=4: O[sp][row, :] = H[row, sp*1024..+1024] @ W2[e][same k][:]. 16 iters.
__global__ __launch_bounds__(256) void k_gemm2(
    const _Float16* __restrict__ H, const _Float16* __restrict__ BT,
    const int* __restrict__ counts, float* __restrict__ Obase) {
    int bz = blockIdx.z;
    int e = bz & 7, sp = bz >> 3;
    int cnt = counts[e];
    int p0 = blockIdx.y * 128;
    if (p0 >= cnt) return;
    int rowbase = 0;
    for (int i = 0; i < NE; i++) rowbase += (i < e) ? counts[i] : 0;
    int n0 = blockIdx.x * 128;
    int kh = sp * 1024;
    const _Float16* B = BT + (size_t)e * 4194304;   // tiled: [kt64][nt8][8][128][8]
    float* O = Obase + (size_t)sp * 4194304;

    __shared__ _Float16 As[128 * 64];
    __shared__ _Float16 Bs[128 * 64];

    int tid = threadIdx.x;
    int w = tid >> 6, lane = tid & 63;
    int rq = tid >> 3;
    int cch = (tid & 7) ^ ((tid >> 3) & 7);
    const _Float16* pA[4];
    const _Float16* pB[4];
    _Float16* lA[4];
    _Float16* lB[4];
#pragma unroll
    for (int q = 0; q < 4; q++) {
        int row = q * 32 + rq;
        int r = rowbase + min(p0 + row, cnt - 1);
        pA[q] = H + (size_t)r * DFF + kh + cch * 8;
        pB[q] = B + (size_t)(sp * 16) * 65536 + (size_t)n0 * 64 + (q * 256 + tid) * 8;
        lA[q] = As + (q * 256 + w * 64) * 8;
        lB[q] = Bs + (q * 256 + w * 64) * 8;
    }

    int wm = w >> 1, wn = w & 1;
    int lhi = lane >> 4, llo = lane & 15;
    int m7 = llo & 7;
    int kc0 = lhi ^ m7, kc1 = kc0 ^ 4;
    const _Float16* arp0 = As + (wm * 64 + llo) * 64 + kc0 * 8;
    const _Float16* arp1 = As + (wm * 64 + llo) * 64 + kc1 * 8;
    const _Float16* brp0 = Bs + (lhi * 128 + wn * 64 + llo) * 8;
    const _Float16* brp1 = Bs + ((lhi + 4) * 128 + wn * 64 + llo) * 8;

    f32x4 acc[4][4] = {};
    for (int it = 0; it < 16; ++it) {
        __syncthreads();
#pragma unroll
        for (int q = 0; q < 4; q++) { gll(pA[q], lA[q]); gll(pB[q], lB[q]); }
#pragma unroll
        for (int q = 0; q < 4; q++) { pA[q] += 64; pB[q] += 65536; }
        __syncthreads();
        f16x8 a[4], b[4];
#pragma unroll
        for (int i = 0; i < 4; i++) {
            a[i] = *(const f16x8*)(arp0 + i * 1024);
            b[i] = *(const f16x8*)(brp0 + i * 128);
        }
#pragma unroll
        for (int mt = 0; mt < 4; mt++)
#pragma unroll
            for (int nt = 0; nt < 4; nt++)
                acc[mt][nt] = __builtin_amdgcn_mfma_f32_16x16x32_f16(a[mt], b[nt], acc[mt][nt], 0, 0, 0);
#pragma unroll
        for (int i = 0; i < 4; i++) {
            a[i] = *(const f16x8*)(arp1 + i * 1024);
            b[i] = *(const f16x8*)(brp1 + i * 128);
        }
#pragma unroll
        for (int mt = 0; mt < 4; mt++)
#pragma unroll
            for (int nt = 0; nt < 4; nt++)
                acc[mt][nt] = __builtin_amdgcn_mfma_f32_16x16x32_f16(a[mt], b[nt], acc[mt][nt], 0, 0, 0);
    }

#pragma unroll
    for (int mt = 0; mt < 4; mt++) {
#pragma unroll
        for (int i = 0; i < 4; i++) {
            int p = p0 + wm * 64 + mt * 16 + lhi * 4 + i;
            if (p < cnt) {
                size_t o = (size_t)(rowbase + p) * D_EMB + n0 + wn * 64 + llo;
#pragma unroll
                for (int nt = 0; nt < 4; nt++)
                    O[o + nt * 16] = acc[mt][nt][i];
            }
        }
    }
}

// out[t,:] = w0*sum_sp Osp[r0] + w1*sum_sp Osp[r1]
__global__ __launch_bounds__(256) void k_final(
    const float* __restrict__ Obase, const int* __restrict__ counts,
    const int* __restrict__ tok_e, const int* __restrict__ tok_p,
    const float* __restrict__ tok_w, float* __restrict__ out) {
    __shared__ int sb[NE];
    int t = blockIdx.x;
    if (threadIdx.x == 0) {
        int s = 0;
        for (int e = 0; e < NE; e++) { sb[e] = s; s += counts[e]; }
    }
    __syncthreads();
    int r0 = sb[tok_e[t * 2 + 0]] + tok_p[t * 2 + 0];
    int r1 = sb[tok_e[t * 2 + 1]] + tok_p[t * 2 + 1];
    float w0 = tok_w[t * 2 + 0], w1 = tok_w[t * 2 + 1];
    int i = threadIdx.x * 4;
    float4 s0 = {0, 0, 0, 0}, s1 = {0, 0, 0, 0};
#pragma unroll
    for (int sp = 0; sp < 4; sp++) {
        const float* O = Obase + (size_t)sp * 4194304;
        float4 a = *(const float4*)(O + (size_t)r0 * D_EMB + i);
        float4 b = *(const float4*)(O + (size_t)r1 * D_EMB + i);
        s0.x += a.x; s0.y += a.y; s0.z += a.z; s0.w += a.w;
        s1.x += b.x; s1.y += b.y; s1.z += b.z; s1.w += b.w;
    }
    float4 o;
    o.x = w0 * s0.x + w1 * s1.x;
    o.y = w0 * s0.y + w1 * s1.y;
    o.z = w0 * s0.z + w1 * s1.z;
    o.w = w0 * s0.w + w1 * s1.w;
    *(float4*)(out + (size_t)t * D_EMB + i) = o;
}

extern "C" void kernel_launch(void* const* d_in, const int* in_sizes, int n_in,
                              void* d_out, int out_size, void* d_ws, size_t ws_size,
                              hipStream_t stream) {
    const float* x    = (const float*)d_in[0];
    const float* mask = (const float*)d_in[1];
    const float* Wr   = (const float*)d_in[2];
    const float* W1   = (const float*)d_in[3];   // [8,1024,4096]
    const float* W2   = (const float*)d_in[4];   // [8,4096,1024]
    float* out = (float*)d_out;

    char* ws = (char*)d_ws;
    const size_t MB = 1024 * 1024;
    int*      counts = (int*)(ws + 0);
    int*      elist  = (int*)(ws + 1024);
    int*      tok_e  = (int*)(ws + 1024 + 65536);
    int*      tok_p  = (int*)(ws + 1024 + 65536 + 16384);
    float*    tok_w  = (float*)(ws + 1024 + 65536 + 32768);
    _Float16* xh     = (_Float16*)(ws + 1 * MB);    // 4 MB
    _Float16* W1T    = (_Float16*)(ws + 8 * MB);    // 64 MB tiled [e][kt16][nt32][8][128][8]
    _Float16* W2T    = (_Float16*)(ws + 72 * MB);   // 64 MB tiled [e][kt64][nt8][8][128][8]
    _Float16* H      = (_Float16*)(ws + 136 * MB);  // 32 MB [4096][4096]
    float*    Obuf   = (float*)(ws + 168 * MB);     // 64 MB [4 sp][4096][1024]

    k_zero<<<1, 64, 0, stream>>>(counts);
    // router (512 blocks) + transpose W1 (4096 blocks)
    k_f1<<<512 + 4096, 256, 0, stream>>>(x, mask, Wr, xh, counts, elist,
                                         tok_e, tok_p, tok_w, W1, W1T);
    // gemm1 (4096 even blocks) interleaved with transpose W2 (4096 odd blocks)
    k_f2<<<8192, 256, 0, stream>>>(xh, W1T, counts, elist, H, W2, W2T);
    k_gemm2<<<dim3(8, 16, 32), 256, 0, stream>>>(H, W2T, counts, Obuf);
    k_final<<<T_TOK, 256, 0, stream>>>(Obuf, counts, tok_e, tok_p, tok_w, out);
}

// Round 4
// 473.707 us; speedup vs baseline: 1.0654x; 1.0541x over previous
//
#include <hip/hip_runtime.h>
#include <hip/hip_bf16.h>

// MaskedMoE: T=2048, d=1024, d_ff=4096, E=8, top-2.
// R7: no pre-transpose. GEMMs read fp32 weights directly; B-staging converts
//   fp32->fp16 in registers and ds_writes into a chunk-major swizzled LDS tile:
//     Bs plane ch (k-chunk) holds col n at position p(n) = n ^ ((n>>3)&7).
//   Producer (thread t): g=t>>5 owns chunk g, l5=t&31 owns n=4*l5..+3; loads
//   8x float4 (rows g*8..+7), converts, 4x ds_write_b128 (2 lanes/bank = free).
//   Consumer reads plane lhi (and lhi+4) at p(n) (2 lanes/bank = free).
//   XCD-clustered mapping: each XCD owns its n0-slabs; resident blocks share
//   one n0-group -> B working set 4 MB = one L2; weights cross HBM once.
//   A path / MFMA / epilogue identical to R5 (verified absmax 0.0039).

#define T_TOK 2048
#define D_EMB 1024
#define DFF   4096
#define NE    8

typedef _Float16 f16x8 __attribute__((ext_vector_type(8)));
typedef float    f32x4 __attribute__((ext_vector_type(4)));

__device__ __forceinline__ float gelu_tanh(float x) {
    const float c = 0.7978845608028654f;
    float z = c * (x + 0.044715f * x * x * x);
    float u = __expf(2.0f * z);
    return 0.5f * x * (1.0f + (u - 1.0f) / (u + 1.0f));
}

__device__ __forceinline__ void gll(const void* g, void* l) {
    __builtin_amdgcn_global_load_lds((__attribute__((address_space(1))) void*)g,
                                     (__attribute__((address_space(3))) void*)l,
                                     16, 0, 0);
}

__global__ void k_zero(int* counts) {
    if (threadIdx.x < NE) counts[threadIdx.x] = 0;
}

// Router (one wave/token) + fp16 conversion of x fused.
__global__ __launch_bounds__(256) void k_router(
    const float* __restrict__ x, const float* __restrict__ mask,
    const float* __restrict__ Wr, _Float16* __restrict__ xh,
    int* __restrict__ counts, int* __restrict__ elist,
    int* __restrict__ tok_e, int* __restrict__ tok_p, float* __restrict__ tok_w) {
    int wave = threadIdx.x >> 6;
    int lane = threadIdx.x & 63;
    int t = blockIdx.x * 4 + wave;
    if (t >= T_TOK) return;

    float acc[NE];
#pragma unroll
    for (int e = 0; e < NE; e++) acc[e] = 0.f;
    const float* xr = x + (size_t)t * D_EMB;
    for (int c = 0; c < D_EMB / 64; c++) {
        int i = c * 64 + lane;
        float xv = xr[i];
        xh[(size_t)t * D_EMB + i] = (_Float16)xv;
        const float* wr = Wr + (size_t)i * NE;
#pragma unroll
        for (int e = 0; e < NE; e++) acc[e] += xv * wr[e];
    }
#pragma unroll
    for (int e = 0; e < NE; e++) {
#pragma unroll
        for (int off = 32; off > 0; off >>= 1)
            acc[e] += __shfl_xor(acc[e], off);
    }
    if (lane == 0) {
        float p[NE];
        float mx = -1e30f;
#pragma unroll
        for (int e = 0; e < NE; e++) {
            p[e] = acc[e] * mask[t * NE + e];
            mx = fmaxf(mx, p[e]);
        }
        float s = 0.f;
#pragma unroll
        for (int e = 0; e < NE; e++) { p[e] = expf(p[e] - mx); s += p[e]; }
#pragma unroll
        for (int e = 0; e < NE; e++) p[e] /= s;
        int e0 = 0; float b0 = p[0];
#pragma unroll
        for (int e = 1; e < NE; e++) if (p[e] > b0) { b0 = p[e]; e0 = e; }
        int e1 = -1; float b1 = -1.f;
#pragma unroll
        for (int e = 0; e < NE; e++) if (e != e0 && p[e] > b1) { b1 = p[e]; e1 = e; }

        int pos0 = atomicAdd(&counts[e0], 1);
        elist[e0 * T_TOK + pos0] = t;
        tok_e[t * 2 + 0] = e0; tok_p[t * 2 + 0] = pos0; tok_w[t * 2 + 0] = b0;
        int pos1 = atomicAdd(&counts[e1], 1);
        elist[e1 * T_TOK + pos1] = t;
        tok_e[t * 2 + 1] = e1; tok_p[t * 2 + 1] = pos1; tok_w[t * 2 + 1] = b1;
    }
}

// ---- GEMM core --------------------------------------------------------------
// A LDS tile: 128 rows x 8 chunks x 8 f16; position p of row r holds chunk p^(r&7).
//   A producer gathers rows with per-lane chunk cch=(tid&7)^((tid>>3)&7) via gll;
//   A consumer: position kc0 = lhi ^ (llo&7), kc1 = kc0^4 (chunks lhi, lhi+4).
// B LDS tile: 8 planes (k-chunk) x 128 n x 8 f16, col n stored at p(n)=n^((n>>3)&7).
//   Producer stages fp32 W directly (reg transpose + cvt), consumer reads
//   plane lhi / lhi+4 at p(n), n = wn*64 + nt*16 + llo.

// GEMM1: H[rowbase+p, :] = gelu(xh[elist[e,p], :] @ W1[e]). K=1024, 16 iters.
// Mapping: xcd=bid&7, local=bid>>3; n0i = xcd*4 + (local>>7); e=(local>>4)&7; pt=local&15.
__global__ __launch_bounds__(256) void k_gemm1(
    const _Float16* __restrict__ xh, const float* __restrict__ W1,
    const int* __restrict__ counts, const int* __restrict__ elist,
    _Float16* __restrict__ H) {
    int bid = blockIdx.x;
    int xcd = bid & 7, local = bid >> 3;
    int n0i = (xcd << 2) | (local >> 7);   // 0..31
    int e   = (local >> 4) & 7;
    int pt  = local & 15;
    int cnt = counts[e];
    int p0 = pt * 128;
    if (p0 >= cnt) return;
    int rowbase = 0;
    for (int i = 0; i < NE; i++) rowbase += (i < e) ? counts[i] : 0;
    int n0 = n0i * 128;
    const float* Bsrc = W1 + (size_t)e * 4194304;   // [1024][4096] fp32

    __shared__ _Float16 As[128 * 64];
    __shared__ _Float16 Bs[8 * 128 * 8];
    __shared__ int ttok[128];

    int tid = threadIdx.x;
    if (tid < 128) ttok[tid] = elist[e * T_TOK + min(p0 + tid, cnt - 1)];
    __syncthreads();

    int w = tid >> 6, lane = tid & 63;
    int rq = tid >> 3;
    int cch = (tid & 7) ^ ((tid >> 3) & 7);
    const _Float16* pA[4];
    _Float16* lA[4];
#pragma unroll
    for (int q = 0; q < 4; q++) {
        int row = q * 32 + rq;
        pA[q] = xh + (size_t)ttok[row] * D_EMB + cch * 8;
        lA[q] = As + (q * 256 + w * 64) * 8;
    }

    // B producer: chunk g = tid>>5, cols 4*l5..+3
    int g = tid >> 5, l5 = tid & 31;
    const float* pB = Bsrc + (size_t)(g * 8) * 4096 + n0 + l5 * 4;
    int xr = (l5 >> 1) & 7;
    _Float16* wp[4];
#pragma unroll
    for (int j = 0; j < 4; j++)
        wp[j] = Bs + g * 1024 + (((4 * l5 + j) ^ xr) * 8);

    int wm = w >> 1, wn = w & 1;
    int lhi = lane >> 4, llo = lane & 15;
    int m7 = llo & 7;
    int kc0 = lhi ^ m7, kc1 = kc0 ^ 4;
    const _Float16* arp0 = As + (wm * 64 + llo) * 64 + kc0 * 8;
    const _Float16* arp1 = As + (wm * 64 + llo) * 64 + kc1 * 8;
    int bofs[4];
#pragma unroll
    for (int nt = 0; nt < 4; nt++) {
        int n = wn * 64 + nt * 16 + llo;
        bofs[nt] = lhi * 1024 + ((n ^ ((n >> 3) & 7)) * 8);
    }

    f32x4 acc[4][4] = {};
    for (int it = 0; it < 16; ++it) {
        __syncthreads();
        f32x4 v[8];
#pragma unroll
        for (int r = 0; r < 8; r++)
            v[r] = *(const f32x4*)(pB + (size_t)r * 4096);
#pragma unroll
        for (int q = 0; q < 4; q++) gll(pA[q], lA[q]);
        f16x8 o[4];
#pragma unroll
        for (int j = 0; j < 4; j++)
#pragma unroll
            for (int u = 0; u < 8; u++)
                o[j][u] = (_Float16)v[u][j];
#pragma unroll
        for (int j = 0; j < 4; j++) *(f16x8*)wp[j] = o[j];
        pB += 64 * 4096;
#pragma unroll
        for (int q = 0; q < 4; q++) pA[q] += 64;
        __syncthreads();
        f16x8 a[4], b[4];
#pragma unroll
        for (int i = 0; i < 4; i++) {
            a[i] = *(const f16x8*)(arp0 + i * 1024);
            b[i] = *(const f16x8*)(Bs + bofs[i]);
        }
#pragma unroll
        for (int mt = 0; mt < 4; mt++)
#pragma unroll
            for (int nt = 0; nt < 4; nt++)
                acc[mt][nt] = __builtin_amdgcn_mfma_f32_16x16x32_f16(a[mt], b[nt], acc[mt][nt], 0, 0, 0);
#pragma unroll
        for (int i = 0; i < 4; i++) {
            a[i] = *(const f16x8*)(arp1 + i * 1024);
            b[i] = *(const f16x8*)(Bs + bofs[i] + 4096);
        }
#pragma unroll
        for (int mt = 0; mt < 4; mt++)
#pragma unroll
            for (int nt = 0; nt < 4; nt++)
                acc[mt][nt] = __builtin_amdgcn_mfma_f32_16x16x32_f16(a[mt], b[nt], acc[mt][nt], 0, 0, 0);
    }

#pragma unroll
    for (int mt = 0; mt < 4; mt++) {
#pragma unroll
        for (int i = 0; i < 4; i++) {
            int p = p0 + wm * 64 + mt * 16 + lhi * 4 + i;
            if (p < cnt) {
                size_t rowoff = (size_t)(rowbase + p) * DFF + n0 + wn * 64 + llo;
#pragma unroll
                for (int nt = 0; nt < 4; nt++)
                    H[rowoff + nt * 16] = (_Float16)gelu_tanh(acc[mt][nt][i]);
            }
        }
    }
}

// GEMM2 split-K=4: O[sp][row, :] = H[row, sp*1024..+1024] @ W2[e][same k][:]. 16 iters.
// Mapping: xcd=bid&7, local=bid>>3; g2 = xcd*32 + (local>>4); pt=local&15;
//          e = g2&7, sp = (g2>>3)&3, n0i = g2>>5 (0..7).
__global__ __launch_bounds__(256) void k_gemm2(
    const _Float16* __restrict__ H, const float* __restrict__ W2,
    const int* __restrict__ counts, float* __restrict__ Obase) {
    int bid = blockIdx.x;
    int xcd = bid & 7, local = bid >> 3;
    int g2 = (xcd << 5) | (local >> 4);    // 0..255
    int pt = local & 15;
    int e = g2 & 7, sp = (g2 >> 3) & 3, n0i = g2 >> 5;
    int cnt = counts[e];
    int p0 = pt * 128;
    if (p0 >= cnt) return;
    int rowbase = 0;
    for (int i = 0; i < NE; i++) rowbase += (i < e) ? counts[i] : 0;
    int n0 = n0i * 128;
    int kh = sp * 1024;
    const float* Bsrc = W2 + (size_t)e * 4194304;   // [4096][1024] fp32
    float* O = Obase + (size_t)sp * 4194304;

    __shared__ _Float16 As[128 * 64];
    __shared__ _Float16 Bs[8 * 128 * 8];

    int tid = threadIdx.x;
    int w = tid >> 6, lane = tid & 63;
    int rq = tid >> 3;
    int cch = (tid & 7) ^ ((tid >> 3) & 7);
    const _Float16* pA[4];
    _Float16* lA[4];
#pragma unroll
    for (int q = 0; q < 4; q++) {
        int row = q * 32 + rq;
        int r = rowbase + min(p0 + row, cnt - 1);
        pA[q] = H + (size_t)r * DFF + kh + cch * 8;
        lA[q] = As + (q * 256 + w * 64) * 8;
    }

    int g = tid >> 5, l5 = tid & 31;
    const float* pB = Bsrc + (size_t)(kh + g * 8) * 1024 + n0 + l5 * 4;
    int xr = (l5 >> 1) & 7;
    _Float16* wp[4];
#pragma unroll
    for (int j = 0; j < 4; j++)
        wp[j] = Bs + g * 1024 + (((4 * l5 + j) ^ xr) * 8);

    int wm = w >> 1, wn = w & 1;
    int lhi = lane >> 4, llo = lane & 15;
    int m7 = llo & 7;
    int kc0 = lhi ^ m7, kc1 = kc0 ^ 4;
    const _Float16* arp0 = As + (wm * 64 + llo) * 64 + kc0 * 8;
    const _Float16* arp1 = As + (wm * 64 + llo) * 64 + kc1 * 8;
    int bofs[4];
#pragma unroll
    for (int nt = 0; nt < 4; nt++) {
        int n = wn * 64 + nt * 16 + llo;
        bofs[nt] = lhi * 1024 + ((n ^ ((n >> 3) & 7)) * 8);
    }

    f32x4 acc[4][4] = {};
    for (int it = 0; it < 16; ++it) {
        __syncthreads();
        f32x4 v[8];
#pragma unroll
        for (int r = 0; r < 8; r++)
            v[r] = *(const f32x4*)(pB + (size_t)r * 1024);
#pragma unroll
        for (int q = 0; q < 4; q++) gll(pA[q], lA[q]);
        f16x8 o[4];
#pragma unroll
        for (int j = 0; j < 4; j++)
#pragma unroll
            for (int u = 0; u < 8; u++)
                o[j][u] = (_Float16)v[u][j];
#pragma unroll
        for (int j = 0; j < 4; j++) *(f16x8*)wp[j] = o[j];
        pB += 64 * 1024;
#pragma unroll
        for (int q = 0; q < 4; q++) pA[q] += 64;
        __syncthreads();
        f16x8 a[4], b[4];
#pragma unroll
        for (int i = 0; i < 4; i++) {
            a[i] = *(const f16x8*)(arp0 + i * 1024);
            b[i] = *(const f16x8*)(Bs + bofs[i]);
        }
#pragma unroll
        for (int mt = 0; mt < 4; mt++)
#pragma unroll
            for (int nt = 0; nt < 4; nt++)
                acc[mt][nt] = __builtin_amdgcn_mfma_f32_16x16x32_f16(a[mt], b[nt], acc[mt][nt], 0, 0, 0);
#pragma unroll
        for (int i = 0; i < 4; i++) {
            a[i] = *(const f16x8*)(arp1 + i * 1024);
            b[i] = *(const f16x8*)(Bs + bofs[i] + 4096);
        }
#pragma unroll
        for (int mt = 0; mt < 4; mt++)
#pragma unroll
            for (int nt = 0; nt < 4; nt++)
                acc[mt][nt] = __builtin_amdgcn_mfma_f32_16x16x32_f16(a[mt], b[nt], acc[mt][nt], 0, 0, 0);
    }

#pragma unroll
    for (int mt = 0; mt < 4; mt++) {
#pragma unroll
        for (int i = 0; i < 4; i++) {
            int p = p0 + wm * 64 + mt * 16 + lhi * 4 + i;
            if (p < cnt) {
                size_t o = (size_t)(rowbase + p) * D_EMB + n0 + wn * 64 + llo;
#pragma unroll
                for (int nt = 0; nt < 4; nt++)
                    O[o + nt * 16] = acc[mt][nt][i];
            }
        }
    }
}

// out[t,:] = w0*sum_sp Osp[r0] + w1*sum_sp Osp[r1]
__global__ __launch_bounds__(256) void k_final(
    const float* __restrict__ Obase, const int* __restrict__ counts,
    const int* __restrict__ tok_e, const int* __restrict__ tok_p,
    const float* __restrict__ tok_w, float* __restrict__ out) {
    __shared__ int sb[NE];
    int t = blockIdx.x;
    if (threadIdx.x == 0) {
        int s = 0;
        for (int e = 0; e < NE; e++) { sb[e] = s; s += counts[e]; }
    }
    __syncthreads();
    int r0 = sb[tok_e[t * 2 + 0]] + tok_p[t * 2 + 0];
    int r1 = sb[tok_e[t * 2 + 1]] + tok_p[t * 2 + 1];
    float w0 = tok_w[t * 2 + 0], w1 = tok_w[t * 2 + 1];
    int i = threadIdx.x * 4;
    float4 s0 = {0, 0, 0, 0}, s1 = {0, 0, 0, 0};
#pragma unroll
    for (int sp = 0; sp < 4; sp++) {
        const float* O = Obase + (size_t)sp * 4194304;
        float4 a = *(const float4*)(O + (size_t)r0 * D_EMB + i);
        float4 b = *(const float4*)(O + (size_t)r1 * D_EMB + i);
        s0.x += a.x; s0.y += a.y; s0.z += a.z; s0.w += a.w;
        s1.x += b.x; s1.y += b.y; s1.z += b.z; s1.w += b.w;
    }
    float4 o;
    o.x = w0 * s0.x + w1 * s1.x;
    o.y = w0 * s0.y + w1 * s1.y;
    o.z = w0 * s0.z + w1 * s1.z;
    o.w = w0 * s0.w + w1 * s1.w;
    *(float4*)(out + (size_t)t * D_EMB + i) = o;
}

extern "C" void kernel_launch(void* const* d_in, const int* in_sizes, int n_in,
                              void* d_out, int out_size, void* d_ws, size_t ws_size,
                              hipStream_t stream) {
    const float* x    = (const float*)d_in[0];
    const float* mask = (const float*)d_in[1];
    const float* Wr   = (const float*)d_in[2];
    const float* W1   = (const float*)d_in[3];   // [8,1024,4096]
    const float* W2   = (const float*)d_in[4];   // [8,4096,1024]
    float* out = (float*)d_out;

    char* ws = (char*)d_ws;
    const size_t MB = 1024 * 1024;
    int*      counts = (int*)(ws + 0);
    int*      elist  = (int*)(ws + 1024);
    int*      tok_e  = (int*)(ws + 1024 + 65536);
    int*      tok_p  = (int*)(ws + 1024 + 65536 + 16384);
    float*    tok_w  = (float*)(ws + 1024 + 65536 + 32768);
    _Float16* xh     = (_Float16*)(ws + 1 * MB);    // 4 MB
    _Float16* H      = (_Float16*)(ws + 8 * MB);    // 32 MB [4096][4096]
    float*    Obuf   = (float*)(ws + 40 * MB);      // 64 MB [4 sp][4096][1024]

    k_zero<<<1, 64, 0, stream>>>(counts);
    k_router<<<T_TOK / 4, 256, 0, stream>>>(x, mask, Wr, xh, counts, elist, tok_e, tok_p, tok_w);
    k_gemm1<<<4096, 256, 0, stream>>>(xh, W1, counts, elist, H);
    k_gemm2<<<4096, 256, 0, stream>>>(H, W2, counts, Obuf);
    k_final<<<T_TOK, 256, 0, stream>>>(Obuf, counts, tok_e, tok_p, tok_w, out);
}

// Round 5
// 468.245 us; speedup vs baseline: 1.0778x; 1.0117x over previous
//
#include <hip/hip_runtime.h>
#include <hip/hip_bf16.h>

// MaskedMoE: T=2048, d=1024, d_ff=4096, E=8, top-2.
// R8: R7 (direct fp32 B-staging, no pre-transpose) + 2-phase software pipeline.
//   Per K-step t: cvt+ds_write B(t) (regs loaded at t-1) -> issue B(t+1) loads +
//   gll A(t+1) into buf c^1 -> s_waitcnt vmcnt(12) (keep the 12 new ops in
//   flight across the barrier; only A(t)'s 4 gll must land) + lgkmcnt(0) ->
//   RAW s_barrier -> MFMA on buf c -> raw barrier. Double-buffered LDS (64KB).
//   Loop fully unrolled: buffer parity + vmcnt literals + v[2][8] rotation all
//   static. B-load latency hides under a full iteration instead of zero.
//   Mapping/epilogue/A-path identical to R7 (verified absmax 0.0039).

#define T_TOK 2048
#define D_EMB 1024
#define DFF   4096
#define NE    8

typedef _Float16 f16x8 __attribute__((ext_vector_type(8)));
typedef float    f32x4 __attribute__((ext_vector_type(4)));

__device__ __forceinline__ float gelu_tanh(float x) {
    const float c = 0.7978845608028654f;
    float z = c * (x + 0.044715f * x * x * x);
    float u = __expf(2.0f * z);
    return 0.5f * x * (1.0f + (u - 1.0f) / (u + 1.0f));
}

__device__ __forceinline__ void gll(const void* g, void* l) {
    __builtin_amdgcn_global_load_lds((__attribute__((address_space(1))) void*)g,
                                     (__attribute__((address_space(3))) void*)l,
                                     16, 0, 0);
}

__global__ void k_zero(int* counts) {
    if (threadIdx.x < NE) counts[threadIdx.x] = 0;
}

// Router (one wave/token) + fp16 conversion of x fused.
__global__ __launch_bounds__(256) void k_router(
    const float* __restrict__ x, const float* __restrict__ mask,
    const float* __restrict__ Wr, _Float16* __restrict__ xh,
    int* __restrict__ counts, int* __restrict__ elist,
    int* __restrict__ tok_e, int* __restrict__ tok_p, float* __restrict__ tok_w) {
    int wave = threadIdx.x >> 6;
    int lane = threadIdx.x & 63;
    int t = blockIdx.x * 4 + wave;
    if (t >= T_TOK) return;

    float acc[NE];
#pragma unroll
    for (int e = 0; e < NE; e++) acc[e] = 0.f;
    const float* xr = x + (size_t)t * D_EMB;
    for (int c = 0; c < D_EMB / 64; c++) {
        int i = c * 64 + lane;
        float xv = xr[i];
        xh[(size_t)t * D_EMB + i] = (_Float16)xv;
        const float* wr = Wr + (size_t)i * NE;
#pragma unroll
        for (int e = 0; e < NE; e++) acc[e] += xv * wr[e];
    }
#pragma unroll
    for (int e = 0; e < NE; e++) {
#pragma unroll
        for (int off = 32; off > 0; off >>= 1)
            acc[e] += __shfl_xor(acc[e], off);
    }
    if (lane == 0) {
        float p[NE];
        float mx = -1e30f;
#pragma unroll
        for (int e = 0; e < NE; e++) {
            p[e] = acc[e] * mask[t * NE + e];
            mx = fmaxf(mx, p[e]);
        }
        float s = 0.f;
#pragma unroll
        for (int e = 0; e < NE; e++) { p[e] = expf(p[e] - mx); s += p[e]; }
#pragma unroll
        for (int e = 0; e < NE; e++) p[e] /= s;
        int e0 = 0; float b0 = p[0];
#pragma unroll
        for (int e = 1; e < NE; e++) if (p[e] > b0) { b0 = p[e]; e0 = e; }
        int e1 = -1; float b1 = -1.f;
#pragma unroll
        for (int e = 0; e < NE; e++) if (e != e0 && p[e] > b1) { b1 = p[e]; e1 = e; }

        int pos0 = atomicAdd(&counts[e0], 1);
        elist[e0 * T_TOK + pos0] = t;
        tok_e[t * 2 + 0] = e0; tok_p[t * 2 + 0] = pos0; tok_w[t * 2 + 0] = b0;
        int pos1 = atomicAdd(&counts[e1], 1);
        elist[e1 * T_TOK + pos1] = t;
        tok_e[t * 2 + 1] = e1; tok_p[t * 2 + 1] = pos1; tok_w[t * 2 + 1] = b1;
    }
}

// ---- GEMM core (2-phase pipelined) ------------------------------------------
// A LDS tile: 128 rows x 8 chunks x 8 f16; position p of row r holds chunk p^(r&7).
// B LDS tile: 8 planes (k-chunk) x 128 n x 8 f16, col n at p(n)=n^((n>>3)&7).
// Double-buffered (plane = 8192 halfwords = 16KB each for As and Bs).

// GEMM1: H[rowbase+p, :] = gelu(xh[elist[e,p], :] @ W1[e]). K=1024, 16 iters.
__global__ __launch_bounds__(256) void k_gemm1(
    const _Float16* __restrict__ xh, const float* __restrict__ W1,
    const int* __restrict__ counts, const int* __restrict__ elist,
    _Float16* __restrict__ H) {
    int bid = blockIdx.x;
    int xcd = bid & 7, local = bid >> 3;
    int n0i = (xcd << 2) | (local >> 7);   // 0..31
    int e   = (local >> 4) & 7;
    int pt  = local & 15;
    int cnt = counts[e];
    int p0 = pt * 128;
    if (p0 >= cnt) return;
    int rowbase = 0;
    for (int i = 0; i < NE; i++) rowbase += (i < e) ? counts[i] : 0;
    int n0 = n0i * 128;
    const float* Bsrc = W1 + (size_t)e * 4194304;   // [1024][4096] fp32

    __shared__ _Float16 As[2][128 * 64];
    __shared__ _Float16 Bs[2][8 * 128 * 8];
    __shared__ int ttok[128];

    int tid = threadIdx.x;
    if (tid < 128) ttok[tid] = elist[e * T_TOK + min(p0 + tid, cnt - 1)];
    __syncthreads();

    int w = tid >> 6, lane = tid & 63;
    int rq = tid >> 3;
    int cch = (tid & 7) ^ ((tid >> 3) & 7);
    const _Float16* pA[4];
    _Float16* lA[4];
#pragma unroll
    for (int q = 0; q < 4; q++) {
        int row = q * 32 + rq;
        pA[q] = xh + (size_t)ttok[row] * D_EMB + cch * 8;
        lA[q] = As[0] + (q * 256 + w * 64) * 8;
    }

    // B producer: chunk g = tid>>5, cols 4*l5..+3
    int g = tid >> 5, l5 = tid & 31;
    const float* pB = Bsrc + (size_t)(g * 8) * 4096 + n0 + l5 * 4;
    int xr = (l5 >> 1) & 7;
    _Float16* wp[4];
#pragma unroll
    for (int j = 0; j < 4; j++)
        wp[j] = Bs[0] + g * 1024 + (((4 * l5 + j) ^ xr) * 8);

    int wm = w >> 1, wn = w & 1;
    int lhi = lane >> 4, llo = lane & 15;
    int m7 = llo & 7;
    int kc0 = lhi ^ m7, kc1 = kc0 ^ 4;
    const _Float16* arp0 = As[0] + (wm * 64 + llo) * 64 + kc0 * 8;
    const _Float16* arp1 = As[0] + (wm * 64 + llo) * 64 + kc1 * 8;
    int bofs[4];
#pragma unroll
    for (int nt = 0; nt < 4; nt++) {
        int n = wn * 64 + nt * 16 + llo;
        bofs[nt] = lhi * 1024 + ((n ^ ((n >> 3) & 7)) * 8);
    }

    // prologue: stage tile 0 (B regs + A gll into buffer 0)
    f32x4 v[2][8];
#pragma unroll
    for (int r = 0; r < 8; r++) v[0][r] = *(const f32x4*)(pB + (size_t)r * 4096);
#pragma unroll
    for (int q = 0; q < 4; q++) gll(pA[q], lA[q]);
    pB += (size_t)64 * 4096;
#pragma unroll
    for (int q = 0; q < 4; q++) pA[q] += 64;

    f32x4 acc[4][4] = {};
#pragma unroll
    for (int it = 0; it < 16; ++it) {
        const int c = it & 1;
        // 1. convert + LDS-write current B tile into Bs[c]
        f16x8 o[4];
#pragma unroll
        for (int j = 0; j < 4; j++)
#pragma unroll
            for (int u = 0; u < 8; u++)
                o[j][u] = (_Float16)v[c][u][j];
#pragma unroll
        for (int j = 0; j < 4; j++) *(f16x8*)(wp[j] + c * 8192) = o[j];
        // 2. stage tile t+1 (stays in flight across the barrier)
        if (it < 15) {
#pragma unroll
            for (int r = 0; r < 8; r++)
                v[c ^ 1][r] = *(const f32x4*)(pB + (size_t)r * 4096);
#pragma unroll
            for (int q = 0; q < 4; q++) gll(pA[q], lA[q] + (c ^ 1) * 8192);
            pB += (size_t)64 * 4096;
#pragma unroll
            for (int q = 0; q < 4; q++) pA[q] += 64;
            asm volatile("s_waitcnt vmcnt(12) lgkmcnt(0)" ::: "memory");
        } else {
            asm volatile("s_waitcnt vmcnt(0) lgkmcnt(0)" ::: "memory");
        }
        __builtin_amdgcn_s_barrier();
        __builtin_amdgcn_sched_barrier(0);
        // 3. MFMA on buffer c
        const _Float16* a0 = arp0 + c * 8192;
        const _Float16* a1 = arp1 + c * 8192;
        const _Float16* Bc = Bs[c];
        f16x8 a[4], b[4];
#pragma unroll
        for (int i = 0; i < 4; i++) {
            a[i] = *(const f16x8*)(a0 + i * 1024);
            b[i] = *(const f16x8*)(Bc + bofs[i]);
        }
#pragma unroll
        for (int mt = 0; mt < 4; mt++)
#pragma unroll
            for (int nt = 0; nt < 4; nt++)
                acc[mt][nt] = __builtin_amdgcn_mfma_f32_16x16x32_f16(a[mt], b[nt], acc[mt][nt], 0, 0, 0);
#pragma unroll
        for (int i = 0; i < 4; i++) {
            a[i] = *(const f16x8*)(a1 + i * 1024);
            b[i] = *(const f16x8*)(Bc + bofs[i] + 4096);
        }
#pragma unroll
        for (int mt = 0; mt < 4; mt++)
#pragma unroll
            for (int nt = 0; nt < 4; nt++)
                acc[mt][nt] = __builtin_amdgcn_mfma_f32_16x16x32_f16(a[mt], b[nt], acc[mt][nt], 0, 0, 0);
        __builtin_amdgcn_s_barrier();
    }

#pragma unroll
    for (int mt = 0; mt < 4; mt++) {
#pragma unroll
        for (int i = 0; i < 4; i++) {
            int p = p0 + wm * 64 + mt * 16 + lhi * 4 + i;
            if (p < cnt) {
                size_t rowoff = (size_t)(rowbase + p) * DFF + n0 + wn * 64 + llo;
#pragma unroll
                for (int nt = 0; nt < 4; nt++)
                    H[rowoff + nt * 16] = (_Float16)gelu_tanh(acc[mt][nt][i]);
            }
        }
    }
}

// GEMM2 split-K=4: O[sp][row, :] = H[row, sp*1024..+1024] @ W2[e][same k][:]. 16 iters.
__global__ __launch_bounds__(256) void k_gemm2(
    const _Float16* __restrict__ H, const float* __restrict__ W2,
    const int* __restrict__ counts, float* __restrict__ Obase) {
    int bid = blockIdx.x;
    int xcd = bid & 7, local = bid >> 3;
    int g2 = (xcd << 5) | (local >> 4);    // 0..255
    int pt = local & 15;
    int e = g2 & 7, sp = (g2 >> 3) & 3, n0i = g2 >> 5;
    int cnt = counts[e];
    int p0 = pt * 128;
    if (p0 >= cnt) return;
    int rowbase = 0;
    for (int i = 0; i < NE; i++) rowbase += (i < e) ? counts[i] : 0;
    int n0 = n0i * 128;
    int kh = sp * 1024;
    const float* Bsrc = W2 + (size_t)e * 4194304;   // [4096][1024] fp32
    float* O = Obase + (size_t)sp * 4194304;

    __shared__ _Float16 As[2][128 * 64];
    __shared__ _Float16 Bs[2][8 * 128 * 8];

    int tid = threadIdx.x;
    int w = tid >> 6, lane = tid & 63;
    int rq = tid >> 3;
    int cch = (tid & 7) ^ ((tid >> 3) & 7);
    const _Float16* pA[4];
    _Float16* lA[4];
#pragma unroll
    for (int q = 0; q < 4; q++) {
        int row = q * 32 + rq;
        int r = rowbase + min(p0 + row, cnt - 1);
        pA[q] = H + (size_t)r * DFF + kh + cch * 8;
        lA[q] = As[0] + (q * 256 + w * 64) * 8;
    }

    int g = tid >> 5, l5 = tid & 31;
    const float* pB = Bsrc + (size_t)(kh + g * 8) * 1024 + n0 + l5 * 4;
    int xr = (l5 >> 1) & 7;
    _Float16* wp[4];
#pragma unroll
    for (int j = 0; j < 4; j++)
        wp[j] = Bs[0] + g * 1024 + (((4 * l5 + j) ^ xr) * 8);

    int wm = w >> 1, wn = w & 1;
    int lhi = lane >> 4, llo = lane & 15;
    int m7 = llo & 7;
    int kc0 = lhi ^ m7, kc1 = kc0 ^ 4;
    const _Float16* arp0 = As[0] + (wm * 64 + llo) * 64 + kc0 * 8;
    const _Float16* arp1 = As[0] + (wm * 64 + llo) * 64 + kc1 * 8;
    int bofs[4];
#pragma unroll
    for (int nt = 0; nt < 4; nt++) {
        int n = wn * 64 + nt * 16 + llo;
        bofs[nt] = lhi * 1024 + ((n ^ ((n >> 3) & 7)) * 8);
    }

    // prologue: stage tile 0
    f32x4 v[2][8];
#pragma unroll
    for (int r = 0; r < 8; r++) v[0][r] = *(const f32x4*)(pB + (size_t)r * 1024);
#pragma unroll
    for (int q = 0; q < 4; q++) gll(pA[q], lA[q]);
    pB += (size_t)64 * 1024;
#pragma unroll
    for (int q = 0; q < 4; q++) pA[q] += 64;

    f32x4 acc[4][4] = {};
#pragma unroll
    for (int it = 0; it < 16; ++it) {
        const int c = it & 1;
        f16x8 o[4];
#pragma unroll
        for (int j = 0; j < 4; j++)
#pragma unroll
            for (int u = 0; u < 8; u++)
                o[j][u] = (_Float16)v[c][u][j];
#pragma unroll
        for (int j = 0; j < 4; j++) *(f16x8*)(wp[j] + c * 8192) = o[j];
        if (it < 15) {
#pragma unroll
            for (int r = 0; r < 8; r++)
                v[c ^ 1][r] = *(const f32x4*)(pB + (size_t)r * 1024);
#pragma unroll
            for (int q = 0; q < 4; q++) gll(pA[q], lA[q] + (c ^ 1) * 8192);
            pB += (size_t)64 * 1024;
#pragma unroll
            for (int q = 0; q < 4; q++) pA[q] += 64;
            asm volatile("s_waitcnt vmcnt(12) lgkmcnt(0)" ::: "memory");
        } else {
            asm volatile("s_waitcnt vmcnt(0) lgkmcnt(0)" ::: "memory");
        }
        __builtin_amdgcn_s_barrier();
        __builtin_amdgcn_sched_barrier(0);
        const _Float16* a0 = arp0 + c * 8192;
        const _Float16* a1 = arp1 + c * 8192;
        const _Float16* Bc = Bs[c];
        f16x8 a[4], b[4];
#pragma unroll
        for (int i = 0; i < 4; i++) {
            a[i] = *(const f16x8*)(a0 + i * 1024);
            b[i] = *(const f16x8*)(Bc + bofs[i]);
        }
#pragma unroll
        for (int mt = 0; mt < 4; mt++)
#pragma unroll
            for (int nt = 0; nt < 4; nt++)
                acc[mt][nt] = __builtin_amdgcn_mfma_f32_16x16x32_f16(a[mt], b[nt], acc[mt][nt], 0, 0, 0);
#pragma unroll
        for (int i = 0; i < 4; i++) {
            a[i] = *(const f16x8*)(a1 + i * 1024);
            b[i] = *(const f16x8*)(Bc + bofs[i] + 4096);
        }
#pragma unroll
        for (int mt = 0; mt < 4; mt++)
#pragma unroll
            for (int nt = 0; nt < 4; nt++)
                acc[mt][nt] = __builtin_amdgcn_mfma_f32_16x16x32_f16(a[mt], b[nt], acc[mt][nt], 0, 0, 0);
        __builtin_amdgcn_s_barrier();
    }

#pragma unroll
    for (int mt = 0; mt < 4; mt++) {
#pragma unroll
        for (int i = 0; i < 4; i++) {
            int p = p0 + wm * 64 + mt * 16 + lhi * 4 + i;
            if (p < cnt) {
                size_t o2 = (size_t)(rowbase + p) * D_EMB + n0 + wn * 64 + llo;
#pragma unroll
                for (int nt = 0; nt < 4; nt++)
                    O[o2 + nt * 16] = acc[mt][nt][i];
            }
        }
    }
}

// out[t,:] = w0*sum_sp Osp[r0] + w1*sum_sp Osp[r1]
__global__ __launch_bounds__(256) void k_final(
    const float* __restrict__ Obase, const int* __restrict__ counts,
    const int* __restrict__ tok_e, const int* __restrict__ tok_p,
    const float* __restrict__ tok_w, float* __restrict__ out) {
    __shared__ int sb[NE];
    int t = blockIdx.x;
    if (threadIdx.x == 0) {
        int s = 0;
        for (int e = 0; e < NE; e++) { sb[e] = s; s += counts[e]; }
    }
    __syncthreads();
    int r0 = sb[tok_e[t * 2 + 0]] + tok_p[t * 2 + 0];
    int r1 = sb[tok_e[t * 2 + 1]] + tok_p[t * 2 + 1];
    float w0 = tok_w[t * 2 + 0], w1 = tok_w[t * 2 + 1];
    int i = threadIdx.x * 4;
    float4 s0 = {0, 0, 0, 0}, s1 = {0, 0, 0, 0};
#pragma unroll
    for (int sp = 0; sp < 4; sp++) {
        const float* O = Obase + (size_t)sp * 4194304;
        float4 a = *(const float4*)(O + (size_t)r0 * D_EMB + i);
        float4 b = *(const float4*)(O + (size_t)r1 * D_EMB + i);
        s0.x += a.x; s0.y += a.y; s0.z += a.z; s0.w += a.w;
        s1.x += b.x; s1.y += b.y; s1.z += b.z; s1.w += b.w;
    }
    float4 o;
    o.x = w0 * s0.x + w1 * s1.x;
    o.y = w0 * s0.y + w1 * s1.y;
    o.z = w0 * s0.z + w1 * s1.z;
    o.w = w0 * s0.w + w1 * s1.w;
    *(float4*)(out + (size_t)t * D_EMB + i) = o;
}

extern "C" void kernel_launch(void* const* d_in, const int* in_sizes, int n_in,
                              void* d_out, int out_size, void* d_ws, size_t ws_size,
                              hipStream_t stream) {
    const float* x    = (const float*)d_in[0];
    const float* mask = (const float*)d_in[1];
    const float* Wr   = (const float*)d_in[2];
    const float* W1   = (const float*)d_in[3];   // [8,1024,4096]
    const float* W2   = (const float*)d_in[4];   // [8,4096,1024]
    float* out = (float*)d_out;

    char* ws = (char*)d_ws;
    const size_t MB = 1024 * 1024;
    int*      counts = (int*)(ws + 0);
    int*      elist  = (int*)(ws + 1024);
    int*      tok_e  = (int*)(ws + 1024 + 65536);
    int*      tok_p  = (int*)(ws + 1024 + 65536 + 16384);
    float*    tok_w  = (float*)(ws + 1024 + 65536 + 32768);
    _Float16* xh     = (_Float16*)(ws + 1 * MB);    // 4 MB
    _Float16* H      = (_Float16*)(ws + 8 * MB);    // 32 MB [4096][4096]
    float*    Obuf   = (float*)(ws + 40 * MB);      // 64 MB [4 sp][4096][1024]

    k_zero<<<1, 64, 0, stream>>>(counts);
    k_router<<<T_TOK / 4, 256, 0, stream>>>(x, mask, Wr, xh, counts, elist, tok_e, tok_p, tok_w);
    k_gemm1<<<4096, 256, 0, stream>>>(xh, W1, counts, elist, H);
    k_gemm2<<<4096, 256, 0, stream>>>(H, W2, counts, Obuf);
    k_final<<<T_TOK, 256, 0, stream>>>(Obuf, counts, tok_e, tok_p, tok_w, out);
}

// Round 6
// 459.252 us; speedup vs baseline: 1.0990x; 1.0196x over previous
//
#include <hip/hip_runtime.h>
#include <hip/hip_bf16.h>

// MaskedMoE: T=2048, d=1024, d_ff=4096, E=8, top-2.
// R9: R8 + B-prefetch depth 2 (3 rotating reg sets, static idx).
//   Iter t: cvt B(t) (regs loaded at t-2, latency fully covered) -> ds_write
//   Bs[t&1] -> issue A(t+1) gll + B(t+2) loads -> s_waitcnt vmcnt(12)
//   (keeps exactly {A(t+1),B(t+2)} in flight, drains A(t)) + lgkmcnt(0) ->
//   raw s_barrier -> MFMA on buf t&1 -> raw barrier.
//   __launch_bounds__(256,2) pins VGPR<=256 (2 blocks/CU, LDS-matched).
//   Mapping/epilogue/A-path identical to R7/R8 (verified absmax 0.0039).

#define T_TOK 2048
#define D_EMB 1024
#define DFF   4096
#define NE    8

typedef _Float16 f16x8 __attribute__((ext_vector_type(8)));
typedef float    f32x4 __attribute__((ext_vector_type(4)));

__device__ __forceinline__ float gelu_tanh(float x) {
    const float c = 0.7978845608028654f;
    float z = c * (x + 0.044715f * x * x * x);
    float u = __expf(2.0f * z);
    return 0.5f * x * (1.0f + (u - 1.0f) / (u + 1.0f));
}

__device__ __forceinline__ void gll(const void* g, void* l) {
    __builtin_amdgcn_global_load_lds((__attribute__((address_space(1))) void*)g,
                                     (__attribute__((address_space(3))) void*)l,
                                     16, 0, 0);
}

__global__ void k_zero(int* counts) {
    if (threadIdx.x < NE) counts[threadIdx.x] = 0;
}

// Router (one wave/token) + fp16 conversion of x fused.
__global__ __launch_bounds__(256) void k_router(
    const float* __restrict__ x, const float* __restrict__ mask,
    const float* __restrict__ Wr, _Float16* __restrict__ xh,
    int* __restrict__ counts, int* __restrict__ elist,
    int* __restrict__ tok_e, int* __restrict__ tok_p, float* __restrict__ tok_w) {
    int wave = threadIdx.x >> 6;
    int lane = threadIdx.x & 63;
    int t = blockIdx.x * 4 + wave;
    if (t >= T_TOK) return;

    float acc[NE];
#pragma unroll
    for (int e = 0; e < NE; e++) acc[e] = 0.f;
    const float* xr = x + (size_t)t * D_EMB;
    for (int c = 0; c < D_EMB / 64; c++) {
        int i = c * 64 + lane;
        float xv = xr[i];
        xh[(size_t)t * D_EMB + i] = (_Float16)xv;
        const float* wr = Wr + (size_t)i * NE;
#pragma unroll
        for (int e = 0; e < NE; e++) acc[e] += xv * wr[e];
    }
#pragma unroll
    for (int e = 0; e < NE; e++) {
#pragma unroll
        for (int off = 32; off > 0; off >>= 1)
            acc[e] += __shfl_xor(acc[e], off);
    }
    if (lane == 0) {
        float p[NE];
        float mx = -1e30f;
#pragma unroll
        for (int e = 0; e < NE; e++) {
            p[e] = acc[e] * mask[t * NE + e];
            mx = fmaxf(mx, p[e]);
        }
        float s = 0.f;
#pragma unroll
        for (int e = 0; e < NE; e++) { p[e] = expf(p[e] - mx); s += p[e]; }
#pragma unroll
        for (int e = 0; e < NE; e++) p[e] /= s;
        int e0 = 0; float b0 = p[0];
#pragma unroll
        for (int e = 1; e < NE; e++) if (p[e] > b0) { b0 = p[e]; e0 = e; }
        int e1 = -1; float b1 = -1.f;
#pragma unroll
        for (int e = 0; e < NE; e++) if (e != e0 && p[e] > b1) { b1 = p[e]; e1 = e; }

        int pos0 = atomicAdd(&counts[e0], 1);
        elist[e0 * T_TOK + pos0] = t;
        tok_e[t * 2 + 0] = e0; tok_p[t * 2 + 0] = pos0; tok_w[t * 2 + 0] = b0;
        int pos1 = atomicAdd(&counts[e1], 1);
        elist[e1 * T_TOK + pos1] = t;
        tok_e[t * 2 + 1] = e1; tok_p[t * 2 + 1] = pos1; tok_w[t * 2 + 1] = b1;
    }
}

// ---- GEMM core (2-phase pipelined, B depth-2) -------------------------------
// A LDS tile: 128 rows x 8 chunks x 8 f16; position p of row r holds chunk p^(r&7).
// B LDS tile: 8 planes (k-chunk) x 128 n x 8 f16, col n at p(n)=n^((n>>3)&7).
// Double-buffered (plane = 8192 halfwords = 16KB each for As and Bs).

// GEMM1: H[rowbase+p, :] = gelu(xh[elist[e,p], :] @ W1[e]). K=1024, 16 iters.
__global__ __launch_bounds__(256, 2) void k_gemm1(
    const _Float16* __restrict__ xh, const float* __restrict__ W1,
    const int* __restrict__ counts, const int* __restrict__ elist,
    _Float16* __restrict__ H) {
    int bid = blockIdx.x;
    int xcd = bid & 7, local = bid >> 3;
    int n0i = (xcd << 2) | (local >> 7);   // 0..31
    int e   = (local >> 4) & 7;
    int pt  = local & 15;
    int cnt = counts[e];
    int p0 = pt * 128;
    if (p0 >= cnt) return;
    int rowbase = 0;
    for (int i = 0; i < NE; i++) rowbase += (i < e) ? counts[i] : 0;
    int n0 = n0i * 128;
    const float* Bsrc = W1 + (size_t)e * 4194304;   // [1024][4096] fp32

    __shared__ _Float16 As[2][128 * 64];
    __shared__ _Float16 Bs[2][8 * 128 * 8];
    __shared__ int ttok[128];

    int tid = threadIdx.x;
    if (tid < 128) ttok[tid] = elist[e * T_TOK + min(p0 + tid, cnt - 1)];
    __syncthreads();

    int w = tid >> 6, lane = tid & 63;
    int rq = tid >> 3;
    int cch = (tid & 7) ^ ((tid >> 3) & 7);
    const _Float16* pA[4];
    _Float16* lA[4];
#pragma unroll
    for (int q = 0; q < 4; q++) {
        int row = q * 32 + rq;
        pA[q] = xh + (size_t)ttok[row] * D_EMB + cch * 8;
        lA[q] = As[0] + (q * 256 + w * 64) * 8;
    }

    // B producer: chunk g = tid>>5, cols 4*l5..+3
    int g = tid >> 5, l5 = tid & 31;
    const float* pB = Bsrc + (size_t)(g * 8) * 4096 + n0 + l5 * 4;
    int xr = (l5 >> 1) & 7;
    _Float16* wp[4];
#pragma unroll
    for (int j = 0; j < 4; j++)
        wp[j] = Bs[0] + g * 1024 + (((4 * l5 + j) ^ xr) * 8);

    int wm = w >> 1, wn = w & 1;
    int lhi = lane >> 4, llo = lane & 15;
    int m7 = llo & 7;
    int kc0 = lhi ^ m7, kc1 = kc0 ^ 4;
    const _Float16* arp0 = As[0] + (wm * 64 + llo) * 64 + kc0 * 8;
    const _Float16* arp1 = As[0] + (wm * 64 + llo) * 64 + kc1 * 8;
    int bofs[4];
#pragma unroll
    for (int nt = 0; nt < 4; nt++) {
        int n = wn * 64 + nt * 16 + llo;
        bofs[nt] = lhi * 1024 + ((n ^ ((n >> 3) & 7)) * 8);
    }

    // prologue: B(0) regs, A(0) gll, B(1) regs  (oldest->newest order matters)
    f32x4 v[3][8];
#pragma unroll
    for (int r = 0; r < 8; r++) v[0][r] = *(const f32x4*)(pB + (size_t)r * 4096);
#pragma unroll
    for (int q = 0; q < 4; q++) gll(pA[q], lA[q]);
#pragma unroll
    for (int r = 0; r < 8; r++) v[1][r] = *(const f32x4*)(pB + (size_t)(64 + r) * 4096);
    pB += (size_t)128 * 4096;
#pragma unroll
    for (int q = 0; q < 4; q++) pA[q] += 64;

    f32x4 acc[4][4] = {};
#pragma unroll
    for (int it = 0; it < 16; ++it) {
        const int c = it & 1;
        const int vc = it % 3;
        // 1. convert + LDS-write B(t) into Bs[c] (regs are 2 iters old: no stall)
        f16x8 o[4];
#pragma unroll
        for (int j = 0; j < 4; j++)
#pragma unroll
            for (int u = 0; u < 8; u++)
                o[j][u] = (_Float16)v[vc][u][j];
#pragma unroll
        for (int j = 0; j < 4; j++) *(f16x8*)(wp[j] + c * 8192) = o[j];
        // 2. issue A(t+1) gll and B(t+2) loads (stay in flight across barrier)
        if (it < 15) {
#pragma unroll
            for (int q = 0; q < 4; q++) gll(pA[q], lA[q] + (c ^ 1) * 8192);
#pragma unroll
            for (int q = 0; q < 4; q++) pA[q] += 64;
        }
        if (it < 14) {
#pragma unroll
            for (int r = 0; r < 8; r++)
                v[(it + 2) % 3][r] = *(const f32x4*)(pB + (size_t)r * 4096);
            pB += (size_t)64 * 4096;
        }
        // 3. counted wait: drain A(t) (and older), keep {A(t+1), B(t+2)}
        if (it < 15) {
            asm volatile("s_waitcnt vmcnt(12) lgkmcnt(0)" ::: "memory");
        } else {
            asm volatile("s_waitcnt vmcnt(0) lgkmcnt(0)" ::: "memory");
        }
        __builtin_amdgcn_s_barrier();
        __builtin_amdgcn_sched_barrier(0);
        // 4. MFMA on buffer c
        const _Float16* a0 = arp0 + c * 8192;
        const _Float16* a1 = arp1 + c * 8192;
        const _Float16* Bc = Bs[c];
        f16x8 a[4], b[4];
#pragma unroll
        for (int i = 0; i < 4; i++) {
            a[i] = *(const f16x8*)(a0 + i * 1024);
            b[i] = *(const f16x8*)(Bc + bofs[i]);
        }
#pragma unroll
        for (int mt = 0; mt < 4; mt++)
#pragma unroll
            for (int nt = 0; nt < 4; nt++)
                acc[mt][nt] = __builtin_amdgcn_mfma_f32_16x16x32_f16(a[mt], b[nt], acc[mt][nt], 0, 0, 0);
#pragma unroll
        for (int i = 0; i < 4; i++) {
            a[i] = *(const f16x8*)(a1 + i * 1024);
            b[i] = *(const f16x8*)(Bc + bofs[i] + 4096);
        }
#pragma unroll
        for (int mt = 0; mt < 4; mt++)
#pragma unroll
            for (int nt = 0; nt < 4; nt++)
                acc[mt][nt] = __builtin_amdgcn_mfma_f32_16x16x32_f16(a[mt], b[nt], acc[mt][nt], 0, 0, 0);
        __builtin_amdgcn_s_barrier();
    }

#pragma unroll
    for (int mt = 0; mt < 4; mt++) {
#pragma unroll
        for (int i = 0; i < 4; i++) {
            int p = p0 + wm * 64 + mt * 16 + lhi * 4 + i;
            if (p < cnt) {
                size_t rowoff = (size_t)(rowbase + p) * DFF + n0 + wn * 64 + llo;
#pragma unroll
                for (int nt = 0; nt < 4; nt++)
                    H[rowoff + nt * 16] = (_Float16)gelu_tanh(acc[mt][nt][i]);
            }
        }
    }
}

// GEMM2 split-K=4: O[sp][row, :] = H[row, sp*1024..+1024] @ W2[e][same k][:]. 16 iters.
__global__ __launch_bounds__(256, 2) void k_gemm2(
    const _Float16* __restrict__ H, const float* __restrict__ W2,
    const int* __restrict__ counts, float* __restrict__ Obase) {
    int bid = blockIdx.x;
    int xcd = bid & 7, local = bid >> 3;
    int g2 = (xcd << 5) | (local >> 4);    // 0..255
    int pt = local & 15;
    int e = g2 & 7, sp = (g2 >> 3) & 3, n0i = g2 >> 5;
    int cnt = counts[e];
    int p0 = pt * 128;
    if (p0 >= cnt) return;
    int rowbase = 0;
    for (int i = 0; i < NE; i++) rowbase += (i < e) ? counts[i] : 0;
    int n0 = n0i * 128;
    int kh = sp * 1024;
    const float* Bsrc = W2 + (size_t)e * 4194304;   // [4096][1024] fp32
    float* O = Obase + (size_t)sp * 4194304;

    __shared__ _Float16 As[2][128 * 64];
    __shared__ _Float16 Bs[2][8 * 128 * 8];

    int tid = threadIdx.x;
    int w = tid >> 6, lane = tid & 63;
    int rq = tid >> 3;
    int cch = (tid & 7) ^ ((tid >> 3) & 7);
    const _Float16* pA[4];
    _Float16* lA[4];
#pragma unroll
    for (int q = 0; q < 4; q++) {
        int row = q * 32 + rq;
        int r = rowbase + min(p0 + row, cnt - 1);
        pA[q] = H + (size_t)r * DFF + kh + cch * 8;
        lA[q] = As[0] + (q * 256 + w * 64) * 8;
    }

    int g = tid >> 5, l5 = tid & 31;
    const float* pB = Bsrc + (size_t)(kh + g * 8) * 1024 + n0 + l5 * 4;
    int xr = (l5 >> 1) & 7;
    _Float16* wp[4];
#pragma unroll
    for (int j = 0; j < 4; j++)
        wp[j] = Bs[0] + g * 1024 + (((4 * l5 + j) ^ xr) * 8);

    int wm = w >> 1, wn = w & 1;
    int lhi = lane >> 4, llo = lane & 15;
    int m7 = llo & 7;
    int kc0 = lhi ^ m7, kc1 = kc0 ^ 4;
    const _Float16* arp0 = As[0] + (wm * 64 + llo) * 64 + kc0 * 8;
    const _Float16* arp1 = As[0] + (wm * 64 + llo) * 64 + kc1 * 8;
    int bofs[4];
#pragma unroll
    for (int nt = 0; nt < 4; nt++) {
        int n = wn * 64 + nt * 16 + llo;
        bofs[nt] = lhi * 1024 + ((n ^ ((n >> 3) & 7)) * 8);
    }

    // prologue: B(0) regs, A(0) gll, B(1) regs
    f32x4 v[3][8];
#pragma unroll
    for (int r = 0; r < 8; r++) v[0][r] = *(const f32x4*)(pB + (size_t)r * 1024);
#pragma unroll
    for (int q = 0; q < 4; q++) gll(pA[q], lA[q]);
#pragma unroll
    for (int r = 0; r < 8; r++) v[1][r] = *(const f32x4*)(pB + (size_t)(64 + r) * 1024);
    pB += (size_t)128 * 1024;
#pragma unroll
    for (int q = 0; q < 4; q++) pA[q] += 64;

    f32x4 acc[4][4] = {};
#pragma unroll
    for (int it = 0; it < 16; ++it) {
        const int c = it & 1;
        const int vc = it % 3;
        f16x8 o[4];
#pragma unroll
        for (int j = 0; j < 4; j++)
#pragma unroll
            for (int u = 0; u < 8; u++)
                o[j][u] = (_Float16)v[vc][u][j];
#pragma unroll
        for (int j = 0; j < 4; j++) *(f16x8*)(wp[j] + c * 8192) = o[j];
        if (it < 15) {
#pragma unroll
            for (int q = 0; q < 4; q++) gll(pA[q], lA[q] + (c ^ 1) * 8192);
#pragma unroll
            for (int q = 0; q < 4; q++) pA[q] += 64;
        }
        if (it < 14) {
#pragma unroll
            for (int r = 0; r < 8; r++)
                v[(it + 2) % 3][r] = *(const f32x4*)(pB + (size_t)r * 1024);
            pB += (size_t)64 * 1024;
        }
        if (it < 15) {
            asm volatile("s_waitcnt vmcnt(12) lgkmcnt(0)" ::: "memory");
        } else {
            asm volatile("s_waitcnt vmcnt(0) lgkmcnt(0)" ::: "memory");
        }
        __builtin_amdgcn_s_barrier();
        __builtin_amdgcn_sched_barrier(0);
        const _Float16* a0 = arp0 + c * 8192;
        const _Float16* a1 = arp1 + c * 8192;
        const _Float16* Bc = Bs[c];
        f16x8 a[4], b[4];
#pragma unroll
        for (int i = 0; i < 4; i++) {
            a[i] = *(const f16x8*)(a0 + i * 1024);
            b[i] = *(const f16x8*)(Bc + bofs[i]);
        }
#pragma unroll
        for (int mt = 0; mt < 4; mt++)
#pragma unroll
            for (int nt = 0; nt < 4; nt++)
                acc[mt][nt] = __builtin_amdgcn_mfma_f32_16x16x32_f16(a[mt], b[nt], acc[mt][nt], 0, 0, 0);
#pragma unroll
        for (int i = 0; i < 4; i++) {
            a[i] = *(const f16x8*)(a1 + i * 1024);
            b[i] = *(const f16x8*)(Bc + bofs[i] + 4096);
        }
#pragma unroll
        for (int mt = 0; mt < 4; mt++)
#pragma unroll
            for (int nt = 0; nt < 4; nt++)
                acc[mt][nt] = __builtin_amdgcn_mfma_f32_16x16x32_f16(a[mt], b[nt], acc[mt][nt], 0, 0, 0);
        __builtin_amdgcn_s_barrier();
    }

#pragma unroll
    for (int mt = 0; mt < 4; mt++) {
#pragma unroll
        for (int i = 0; i < 4; i++) {
            int p = p0 + wm * 64 + mt * 16 + lhi * 4 + i;
            if (p < cnt) {
                size_t o2 = (size_t)(rowbase + p) * D_EMB + n0 + wn * 64 + llo;
#pragma unroll
                for (int nt = 0; nt < 4; nt++)
                    O[o2 + nt * 16] = acc[mt][nt][i];
            }
        }
    }
}

// out[t,:] = w0*sum_sp Osp[r0] + w1*sum_sp Osp[r1]
__global__ __launch_bounds__(256) void k_final(
    const float* __restrict__ Obase, const int* __restrict__ counts,
    const int* __restrict__ tok_e, const int* __restrict__ tok_p,
    const float* __restrict__ tok_w, float* __restrict__ out) {
    __shared__ int sb[NE];
    int t = blockIdx.x;
    if (threadIdx.x == 0) {
        int s = 0;
        for (int e = 0; e < NE; e++) { sb[e] = s; s += counts[e]; }
    }
    __syncthreads();
    int r0 = sb[tok_e[t * 2 + 0]] + tok_p[t * 2 + 0];
    int r1 = sb[tok_e[t * 2 + 1]] + tok_p[t * 2 + 1];
    float w0 = tok_w[t * 2 + 0], w1 = tok_w[t * 2 + 1];
    int i = threadIdx.x * 4;
    float4 s0 = {0, 0, 0, 0}, s1 = {0, 0, 0, 0};
#pragma unroll
    for (int sp = 0; sp < 4; sp++) {
        const float* O = Obase + (size_t)sp * 4194304;
        float4 a = *(const float4*)(O + (size_t)r0 * D_EMB + i);
        float4 b = *(const float4*)(O + (size_t)r1 * D_EMB + i);
        s0.x += a.x; s0.y += a.y; s0.z += a.z; s0.w += a.w;
        s1.x += b.x; s1.y += b.y; s1.z += b.z; s1.w += b.w;
    }
    float4 o;
    o.x = w0 * s0.x + w1 * s1.x;
    o.y = w0 * s0.y + w1 * s1.y;
    o.z = w0 * s0.z + w1 * s1.z;
    o.w = w0 * s0.w + w1 * s1.w;
    *(float4*)(out + (size_t)t * D_EMB + i) = o;
}

extern "C" void kernel_launch(void* const* d_in, const int* in_sizes, int n_in,
                              void* d_out, int out_size, void* d_ws, size_t ws_size,
                              hipStream_t stream) {
    const float* x    = (const float*)d_in[0];
    const float* mask = (const float*)d_in[1];
    const float* Wr   = (const float*)d_in[2];
    const float* W1   = (const float*)d_in[3];   // [8,1024,4096]
    const float* W2   = (const float*)d_in[4];   // [8,4096,1024]
    float* out = (float*)d_out;

    char* ws = (char*)d_ws;
    const size_t MB = 1024 * 1024;
    int*      counts = (int*)(ws + 0);
    int*      elist  = (int*)(ws + 1024);
    int*      tok_e  = (int*)(ws + 1024 + 65536);
    int*      tok_p  = (int*)(ws + 1024 + 65536 + 16384);
    float*    tok_w  = (float*)(ws + 1024 + 65536 + 32768);
    _Float16* xh     = (_Float16*)(ws + 1 * MB);    // 4 MB
    _Float16* H      = (_Float16*)(ws + 8 * MB);    // 32 MB [4096][4096]
    float*    Obuf   = (float*)(ws + 40 * MB);      // 64 MB [4 sp][4096][1024]

    k_zero<<<1, 64, 0, stream>>>(counts);
    k_router<<<T_TOK / 4, 256, 0, stream>>>(x, mask, Wr, xh, counts, elist, tok_e, tok_p, tok_w);
    k_gemm1<<<4096, 256, 0, stream>>>(xh, W1, counts, elist, H);
    k_gemm2<<<4096, 256, 0, stream>>>(H, W2, counts, Obuf);
    k_final<<<T_TOK, 256, 0, stream>>>(Obuf, counts, tok_e, tok_p, tok_w, out);
}